// Round 15
// baseline (912.620 us; speedup 1.0000x reference)
//
#include <hip/hip_runtime.h>
#include <math.h>

#define NN 100000
#define EE 500000
#define NH_C (NN * 128)
#define EBLK 32
// D=H=128, ED=64, T=2, L=4

typedef __attribute__((ext_vector_type(8))) short bf16x8;
typedef __attribute__((ext_vector_type(4))) float f32x4;
typedef __attribute__((ext_vector_type(8))) _Float16 f16x8;
#define MFMA __builtin_amdgcn_mfma_f32_16x16x32_bf16

__device__ inline short f2bf(float x) {
    union { float f; unsigned u; } v; v.f = x;
    unsigned r = v.u + 0x7FFF + ((v.u >> 16) & 1);
    return (short)(r >> 16);
}
__device__ inline float bf2f(unsigned short h) {
    union { unsigned u; float f; } v; v.u = ((unsigned)h) << 16; return v.f;
}
__device__ inline float tanhf_fast(float x) {
    float e = __expf(2.0f * x);
    return 1.0f - 2.0f * __builtin_amdgcn_rcpf(e + 1.0f);
}

__device__ inline bf16x8 mk_hi(const float* p) {
    float4 a = *(const float4*)p, b = *(const float4*)(p + 4);
    float v[8] = {a.x, a.y, a.z, a.w, b.x, b.y, b.z, b.w};
    bf16x8 h;
#pragma unroll
    for (int i = 0; i < 8; i++) h[i] = f2bf(v[i]);
    return h;
}
__device__ inline bf16x8 mk_hi8(float4 a, float4 b) {
    float v[8] = {a.x, a.y, a.z, a.w, b.x, b.y, b.z, b.w};
    bf16x8 h;
#pragma unroll
    for (int i = 0; i < 8; i++) h[i] = f2bf(v[i]);
    return h;
}
__device__ inline void mk_split(const float* p, bf16x8& hi, bf16x8& lo) {
    float4 a = *(const float4*)p, b = *(const float4*)(p + 4);
    float v[8] = {a.x, a.y, a.z, a.w, b.x, b.y, b.z, b.w};
#pragma unroll
    for (int i = 0; i < 8; i++) {
        short h = f2bf(v[i]);
        hi[i] = h;
        lo[i] = f2bf(v[i] - bf2f((unsigned short)h));
    }
}

// ---------------- zero fill ----------------
__global__ void k_zero(float* __restrict__ p, size_t n) {
    size_t i = (size_t)blockIdx.x * blockDim.x + threadIdx.x;
    size_t stride = (size_t)gridDim.x * blockDim.x;
    for (; i < n; i += stride) p[i] = 0.0f;
}
__global__ void k_zeroi(int* __restrict__ p, int n) {
    int i = blockIdx.x * blockDim.x + threadIdx.x;
    if (i < n) p[i] = 0;
}

// ---------------- nf -> bf16 (shared across both relations) ----------------
__global__ __launch_bounds__(256) void k_nfcvt(const float* __restrict__ nf,
                                               unsigned short* __restrict__ nfbf) {
    long gid = (long)blockIdx.x * 256 + threadIdx.x;
    if (gid >= (long)NH_C / 8) return;
    const float* sp = nf + gid * 8;
    f32x4 a = *(const f32x4*)sp;
    f32x4 b = *(const f32x4*)(sp + 4);
    bf16x8 h;
    h[0] = f2bf(a[0]); h[1] = f2bf(a[1]); h[2] = f2bf(a[2]); h[3] = f2bf(a[3]);
    h[4] = f2bf(b[0]); h[5] = f2bf(b[1]); h[6] = f2bf(b[2]); h[7] = f2bf(b[3]);
    *(bf16x8*)(nfbf + gid * 8) = h;
}

// ---------------- CSR build (both relations, concatenated) ----------------
__global__ __launch_bounds__(256) void k_hist2(const int* __restrict__ ei, int* __restrict__ deg2) {
    long g = (long)blockIdx.x * 256 + threadIdx.x;
    if (g < 2L * EE) {
        int t = g >= EE;
        long le = g - (long)t * EE;
        int s = ei[(size_t)t * 2 * EE + le];
        atomicAdd(&deg2[t * NN + s], 1);
    }
}
__global__ __launch_bounds__(512) void k_scan1(const int* __restrict__ deg,
                                               int* __restrict__ tmp, int* __restrict__ bsum) {
    __shared__ int sh[2][512];
    int b = blockIdx.x, tid = threadIdx.x;
    int i = b * 512 + tid;
    int v = (i < 2 * NN) ? deg[i] : 0;
    int cur = 0;
    sh[0][tid] = v;
    __syncthreads();
    for (int off = 1; off < 512; off <<= 1) {
        int nxt = cur ^ 1;
        int a = sh[cur][tid];
        if (tid >= off) a += sh[cur][tid - off];
        sh[nxt][tid] = a;
        __syncthreads();
        cur = nxt;
    }
    int incl = sh[cur][tid];
    if (i < 2 * NN) tmp[i] = incl;
    if (tid == 511) bsum[b] = incl;
}
__global__ __launch_bounds__(512) void k_scan2(const int* __restrict__ bsum, int* __restrict__ boff,
                                               int nB) {
    __shared__ int sh[2][512];
    int tid = threadIdx.x;
    int v = (tid < nB) ? bsum[tid] : 0;
    int cur = 0;
    sh[0][tid] = v;
    __syncthreads();
    for (int off = 1; off < 512; off <<= 1) {
        int nxt = cur ^ 1;
        int a = sh[cur][tid];
        if (tid >= off) a += sh[cur][tid - off];
        sh[nxt][tid] = a;
        __syncthreads();
        cur = nxt;
    }
    boff[tid] = sh[cur][tid] - v;
}
__global__ __launch_bounds__(512) void k_scan3(const int* __restrict__ deg,
                                               const int* __restrict__ tmp,
                                               const int* __restrict__ boff,
                                               int* __restrict__ rowptr, int* __restrict__ cursor) {
    int i = blockIdx.x * 512 + threadIdx.x;
    if (i < 2 * NN) {
        int r = tmp[i] - deg[i] + boff[blockIdx.x];
        rowptr[i] = r;
        cursor[i] = r;
    }
    if (i == 0) rowptr[2 * NN] = 2 * EE;
}
__global__ __launch_bounds__(256) void k_csr_scatter3(const int* __restrict__ ei,
                                                      int* __restrict__ cursor,
                                                      int* __restrict__ ceid,
                                                      int* __restrict__ cs,
                                                      int* __restrict__ cdst) {
    long g = (long)blockIdx.x * 256 + threadIdx.x;
    if (g < 2L * EE) {
        int t = g >= EE;
        long le = g - (long)t * EE;
        int s = ei[(size_t)t * 2 * EE + le];
        int d = ei[(size_t)t * 2 * EE + EE + le];
        int p = atomicAdd(&cursor[t * NN + s], 1);
        ceid[p] = (int)le;
        cs[p] = s;
        cdst[p] = d;
    }
}

// ---------------- level bucketing ----------------
__global__ __launch_bounds__(256) void k_count(const int* __restrict__ lev, int* __restrict__ cnt4) {
    __shared__ int lc[4];
    int tid = threadIdx.x;
    if (tid < 4) lc[tid] = 0;
    __syncthreads();
    for (long n = (long)blockIdx.x * 256 + tid; n < NN; n += (long)gridDim.x * 256)
        atomicAdd(&lc[lev[n]], 1);
    __syncthreads();
    if (tid < 4 && lc[tid]) atomicAdd(&cnt4[tid], lc[tid]);
}

__global__ void k_scan(const int* __restrict__ cnt4, int* __restrict__ off4,
                       int* __restrict__ boff5, int* __restrict__ cursor) {
    int o = 0, b = 0;
    for (int l = 0; l < 4; l++) {
        off4[l] = o; cursor[l] = o; boff5[l] = b;
        o += cnt4[l];
        b += (cnt4[l] + 15) >> 4;
    }
    boff5[4] = b;
}

__global__ __launch_bounds__(256) void k_scatter(const int* __restrict__ lev,
                                                 int* __restrict__ cursor,
                                                 int* __restrict__ perm) {
    __shared__ int lc[4], lb[4], lc2[4];
    int tid = threadIdx.x;
    if (tid < 4) { lc[tid] = 0; lc2[tid] = 0; }
    __syncthreads();
    int start = blockIdx.x * 800, end = start + 800;
    if (end > NN) end = NN;
    for (int n = start + tid; n < end; n += 256) atomicAdd(&lc[lev[n]], 1);
    __syncthreads();
    if (tid < 4 && lc[tid]) lb[tid] = atomicAdd(&cursor[tid], lc[tid]);
    __syncthreads();
    for (int n = start + tid; n < end; n += 256) {
        int l = lev[n];
        int p = atomicAdd(&lc2[l], 1);
        perm[lb[l] + p] = n;
    }
}

// ---------------- prep head (both t): WUT2, WVT2, WET2 (bf16 T), beff2 ----------------
__global__ void k_prep_head2(const float* __restrict__ nlW, const float* __restrict__ nlb,
                             const float* __restrict__ aW1, const float* __restrict__ ab1,
                             const float* __restrict__ neW, const float* __restrict__ neb,
                             unsigned short* __restrict__ WUT2,
                             unsigned short* __restrict__ WVT2, unsigned short* __restrict__ WET2,
                             float* __restrict__ beff2) {
    __shared__ float red[2];
    int t = blockIdx.x >> 7, j = blockIdx.x & 127, k = threadIdx.x;
    const float* Wn = nlW + (size_t)t * 16384;
    const float* bn = nlb + t * 128;
    const float* W1 = aW1 + (size_t)t * 384 * 128;
    const float* b1 = ab1 + t * 128;
    const float* We = neW + (size_t)t * 64 * 128;
    const float* be = neb + t * 128;
    float su = 0.0f, sv = 0.0f;
    for (int m = 0; m < 128; m++) {
        float wkm = Wn[k * 128 + m];
        su = fmaf(wkm, W1[m * 128 + j], su);
        sv = fmaf(wkm, W1[(128 + m) * 128 + j], sv);
    }
    WUT2[(size_t)t * 16384 + j * 128 + k] = (unsigned short)f2bf(su);
    WVT2[(size_t)t * 16384 + j * 128 + k] = (unsigned short)f2bf(sv);
    if (k < 64) {
        float se = 0.0f;
        for (int m = 0; m < 128; m++) se = fmaf(We[k * 128 + m], W1[(256 + m) * 128 + j], se);
        WET2[(size_t)t * 8192 + j * 64 + k] = (unsigned short)f2bf(se);
    }
    float tk = bn[k] * (W1[k * 128 + j] + W1[(128 + k) * 128 + j]) + be[k] * W1[(256 + k) * 128 + j];
#pragma unroll
    for (int o = 32; o > 0; o >>= 1) tk += __shfl_down(tk, o);
    if ((k & 63) == 0) red[k >> 6] = tk;
    __syncthreads();
    if (k == 0) beff2[t * 128 + j] = b1[j] + red[0] + red[1];
}

// ---------------- prep tail: split-bf16 transposed weights (4 mats) ----------------
struct WSrc { const float* s[4]; };
__global__ void k_prep_tail(WSrc ps, unsigned short* __restrict__ hi,
                            unsigned short* __restrict__ lo) {
    int m = blockIdx.x >> 6, blk = blockIdx.x & 63;
    const float* src = ps.s[m];
    unsigned short* h = hi + (size_t)m * 16384;
    unsigned short* l = lo + (size_t)m * 16384;
    int idx = blk * 256 + threadIdx.x;
    int k = idx >> 7, j = idx & 127;
    float v = src[idx];
    short hh = f2bf(v);
    h[j * 128 + k] = (unsigned short)hh;
    l[j * 128 + k] = (unsigned short)f2bf(v - bf2f((unsigned short)hh));
}

// ---------------- prep fold: oWf[t] = Wn[t]@oW[t] (T split bf16); obf = bn@oW + ob ----------
__global__ void k_prep_fold(const float* __restrict__ nlW, const float* __restrict__ nlb,
                            const float* __restrict__ oW, const float* __restrict__ ob,
                            unsigned short* __restrict__ foldhi, unsigned short* __restrict__ foldlo,
                            float* __restrict__ obf) {
    int gidx = blockIdx.x * 256 + threadIdx.x;
    if (gidx < 2 * 16384) {
        int t = gidx >> 14, rem = gidx & 16383;
        int k = rem >> 7, j = rem & 127;
        const float* wn = nlW + (size_t)t * 16384 + (size_t)k * 128;
        const float* ow = oW + (size_t)t * 16384;
        float v = 0.0f;
        for (int m = 0; m < 128; m++) v = fmaf(wn[m], ow[m * 128 + j], v);
        short hh = f2bf(v);
        foldhi[(size_t)t * 16384 + j * 128 + k] = (unsigned short)hh;
        foldlo[(size_t)t * 16384 + j * 128 + k] = (unsigned short)f2bf(v - bf2f((unsigned short)hh));
    } else {
        int e = gidx - 2 * 16384;
        if (e < 256) {
            int t = e >> 7, j = e & 127;
            float v = ob[t * 128 + j];
            for (int m = 0; m < 128; m++)
                v = fmaf(nlb[t * 128 + m], oW[(size_t)t * 16384 + m * 128 + j], v);
            obf[t * 128 + j] = v;
        }
    }
}

// ---------------- prep Q: QW[l] = hpW[l] @ hW1a (T split bf16), qb[l] = hpb[l]@hW1a ----------
__global__ void k_prep_q(const float* __restrict__ hpW, const float* __restrict__ hpb,
                         const float* __restrict__ hW1a,
                         unsigned short* __restrict__ QWhi, unsigned short* __restrict__ QWlo,
                         float* __restrict__ qb) {
    int gidx = blockIdx.x * 256 + threadIdx.x;
    if (gidx < 4 * 16384) {
        int l = gidx >> 14, rem = gidx & 16383;
        int k = rem >> 7, j = rem & 127;
        const float* wr = hpW + (size_t)l * 16384 + (size_t)k * 128;
        float v = 0.0f;
        for (int m = 0; m < 128; m++) v = fmaf(wr[m], hW1a[m * 128 + j], v);
        short hh = f2bf(v);
        QWhi[(size_t)l * 16384 + j * 128 + k] = (unsigned short)hh;
        QWlo[(size_t)l * 16384 + j * 128 + k] = (unsigned short)f2bf(v - bf2f((unsigned short)hh));
    } else {
        int e = gidx - 4 * 16384;
        if (e < 512) {
            int l = e >> 7, j = e & 127;
            float v = 0.0f;
            for (int m = 0; m < 128; m++) v = fmaf(hpb[l * 128 + m], hW1a[m * 128 + j], v);
            qb[l * 128 + j] = v;
        }
    }
}

// ---------------- HEAD2C: both t from one nf tile -> U,V (x2) in fp16 ----------------
__global__ __launch_bounds__(256) void k_head2c(const float* __restrict__ nf,
                                                const unsigned short* __restrict__ WUT2,
                                                const unsigned short* __restrict__ WVT2,
                                                _Float16* __restrict__ U2,
                                                _Float16* __restrict__ V2) {
    __shared__ __align__(16) float T[16][132];
    int tid = threadIdx.x;
    long row0 = (long)blockIdx.x * 16;
#pragma unroll
    for (int i = 0; i < 8; i++) {
        int idx = tid + i * 256;
        int r = idx >> 7, c = idx & 127;
        T[r][c] = nf[(row0 + r) * 128 + c];
    }
    __syncthreads();
    int w = tid >> 6, lane = tid & 63, lr = lane & 15, lg = lane >> 4;
    bf16x8 A[4];
#pragma unroll
    for (int k = 0; k < 4; k++) A[k] = mk_hi(&T[lr][k * 32 + lg * 8]);
    int col0 = w * 32 + lr, col1 = col0 + 16;
#pragma unroll
    for (int o = 0; o < 4; o++) {
        int t = o >> 1, uv = o & 1;
        const unsigned short* wb = (uv ? WVT2 : WUT2) + (size_t)t * 16384;
        _Float16* ob = (uv ? V2 : U2) + (size_t)t * NH_C;
        const unsigned short* w0 = wb + (size_t)col0 * 128 + lg * 8;
        const unsigned short* w1 = wb + (size_t)col1 * 128 + lg * 8;
        f32x4 a0 = {0.f, 0.f, 0.f, 0.f}, a1 = {0.f, 0.f, 0.f, 0.f};
#pragma unroll
        for (int k = 0; k < 4; k++) {
            a0 = MFMA(A[k], *(const bf16x8*)(w0 + k * 32), a0, 0, 0, 0);
            a1 = MFMA(A[k], *(const bf16x8*)(w1 + k * 32), a1, 0, 0, 0);
        }
        _Float16* op = ob + (size_t)row0 * 128;
#pragma unroll
        for (int i = 0; i < 4; i++) {
            int r = lg * 4 + i;
            op[(size_t)r * 128 + col0] = (_Float16)a0[i];
            op[(size_t)r * 128 + col1] = (_Float16)a1[i];
        }
    }
}

// ---------------- EDGE6 (CSR order): fp16 U/V, pk_add stage, XOR-swizzled LDS ----------
__global__ __launch_bounds__(256) void k_edge6(const float* __restrict__ ef,
                                               const int* __restrict__ ceid,
                                               const int* __restrict__ cs,
                                               const int* __restrict__ cdst,
                                               const unsigned short* __restrict__ WET2,
                                               const _Float16* __restrict__ U2,
                                               const _Float16* __restrict__ V2,
                                               const float* __restrict__ beff2,
                                               const float* __restrict__ aW2,
                                               const float* __restrict__ ab2,
                                               float* __restrict__ ebuf2) {
    __shared__ __align__(16) _Float16 preh[EBLK][136];
    __shared__ float part[4][EBLK];
    __shared__ int eS[EBLK];
    int tid = threadIdx.x, w = tid >> 6, lane = tid & 63, lr = lane & 15, lg = lane >> 4;
    long p0 = (long)blockIdx.x * EBLK;
    int t = p0 >= (long)EE;
    const float* ef_t = ef + (size_t)t * EE * 64;
    const _Float16* U_t = U2 + (size_t)t * NH_C;
    const _Float16* V_t = V2 + (size_t)t * NH_C;
    // ---- stage pre = U[s] + V[d]; 8 threads/edge, fp16 pk_add, XOR-swizzled store ----
    {
        int eL = tid >> 3, sub = tid & 7;
        long p = p0 + eL;
        int s = cs[p], d = cdst[p];
        const f16x8* up = (const f16x8*)(U_t + (size_t)s * 128 + sub * 16);
        const f16x8* vp = (const f16x8*)(V_t + (size_t)d * 128 + sub * 16);
        f16x8 s0 = up[0] + vp[0];
        f16x8 s1 = up[1] + vp[1];
        int x = eL & 7;
        *(f16x8*)&preh[eL][((sub * 2) ^ x) << 3] = s0;
        *(f16x8*)&preh[eL][((sub * 2 + 1) ^ x) << 3] = s1;
    }
    if (tid < EBLK) eS[tid] = ceid[p0 + tid];
    int col0 = w * 32 + lr, col1 = col0 + 16;
    int c0b = col0 >> 3, c0r = col0 & 7;
    int c1b = col1 >> 3, c1r = col1 & 7;
    bf16x8 B0[2], B1[2];
#pragma unroll
    for (int kk = 0; kk < 2; kk++) {
        B0[kk] = *(const bf16x8*)(WET2 + (size_t)t * 8192 + (size_t)col0 * 64 + kk * 32 + lg * 8);
        B1[kk] = *(const bf16x8*)(WET2 + (size_t)t * 8192 + (size_t)col1 * 64 + kk * 32 + lg * 8);
    }
    float be0 = beff2[t * 128 + col0], be1 = beff2[t * 128 + col1];
    float w20 = aW2[t * 128 + col0], w21 = aW2[t * 128 + col1];
    __syncthreads();
#pragma unroll
    for (int i16 = 0; i16 < 2; i16++) {
        int e = eS[i16 * 16 + lr];
        const float* ep = ef_t + (size_t)e * 64 + lg * 8;
        float4 L0 = *(const float4*)ep;
        float4 L1 = *(const float4*)(ep + 4);
        float4 L2 = *(const float4*)(ep + 32);
        float4 L3 = *(const float4*)(ep + 36);
        bf16x8 av0 = mk_hi8(L0, L1);
        bf16x8 av1 = mk_hi8(L2, L3);
        f32x4 a0 = {0.f, 0.f, 0.f, 0.f}, a1 = {0.f, 0.f, 0.f, 0.f};
        a0 = MFMA(av0, B0[0], a0, 0, 0, 0);
        a0 = MFMA(av1, B0[1], a0, 0, 0, 0);
        a1 = MFMA(av0, B1[0], a1, 0, 0, 0);
        a1 = MFMA(av1, B1[1], a1, 0, 0, 0);
#pragma unroll
        for (int q = 0; q < 4; q++) {
            int eL = i16 * 16 + lg * 4 + q;
            int x = eL & 7;
            float p0v = (float)preh[eL][((c0b ^ x) << 3) | c0r];
            float p1v = (float)preh[eL][((c1b ^ x) << 3) | c1r];
            float v = tanhf_fast(a0[q] + p0v + be0) * w20 +
                      tanhf_fast(a1[q] + p1v + be1) * w21;
            v += __shfl_xor(v, 1);
            v += __shfl_xor(v, 2);
            v += __shfl_xor(v, 4);
            v += __shfl_xor(v, 8);
            if (lr == 0) part[w][eL] = v;
        }
    }
    __syncthreads();
    if (tid < EBLK) {
        float a = part[0][tid] + part[1][tid] + part[2][tid] + part[3][tid] + ab2[t];
        ebuf2[p0 + tid] = __expf(a);
    }
}

// ---------------- TAIL-A2C (both t): CSR gather of nfbf + folded GEMM + LN + score ---------
__global__ __launch_bounds__(256) void k_tailA2c(const int* __restrict__ rowptr2,
                                                 const int* __restrict__ cdst,
                                                 const float* __restrict__ ebufC,
                                                 const unsigned short* __restrict__ nfbf,
                                                 const unsigned short* __restrict__ foldhi,
                                                 const unsigned short* __restrict__ foldlo,
                                                 const unsigned short* __restrict__ twhi,
                                                 const float* __restrict__ obf,
                                                 const float* __restrict__ lng,
                                                 const float* __restrict__ lnb,
                                                 const float* __restrict__ eb1,
                                                 const float* __restrict__ eW2,
                                                 const float* __restrict__ eb2,
                                                 float* __restrict__ emb0,
                                                 float* __restrict__ emb1,
                                                 float* __restrict__ scores, int NBn) {
    __shared__ __align__(16) float T[16][132];
    __shared__ __align__(16) float T2[16][132];
    __shared__ float mu16[16], rs16[16], part[4][16];
    int tid = threadIdx.x;
    int t = blockIdx.x >= NBn;
    int bi = blockIdx.x - t * NBn;
    long row0 = (long)bi * 16;
    const int* rowp = rowptr2 + (size_t)t * NN;
    const unsigned short* Whi = foldhi + (size_t)t * 16384;
    const unsigned short* Wlo = foldlo + (size_t)t * 16384;
    const unsigned short* Shi = twhi + (size_t)t * 16384;
    const float* ob_t = obf + t * 128;
    const float* g_t = lng + t * 128;
    const float* bln_t = lnb + t * 128;
    const float* sb1 = eb1 + t * 128;
    const float* sW2 = eW2 + t * 128;
    float* emb = t ? emb1 : emb0;
    // CSR gather of nfbf (shared for both t): 16 threads/row, 4-way unrolled
    {
        int r16 = tid >> 4, sub = tid & 15;
        long n = row0 + r16;
        int p0 = rowp[n], p1 = rowp[n + 1];
        float acc[8] = {0, 0, 0, 0, 0, 0, 0, 0};
        float sev = 0.0f;
        int p = p0;
        for (; p + 4 <= p1; p += 4) {
            int d0 = cdst[p], d1 = cdst[p + 1], d2 = cdst[p + 2], d3 = cdst[p + 3];
            float ev0 = ebufC[p], ev1 = ebufC[p + 1];
            float ev2 = ebufC[p + 2], ev3 = ebufC[p + 3];
            bf16x8 h0 = *(const bf16x8*)(nfbf + (size_t)d0 * 128 + sub * 8);
            bf16x8 h1 = *(const bf16x8*)(nfbf + (size_t)d1 * 128 + sub * 8);
            bf16x8 h2 = *(const bf16x8*)(nfbf + (size_t)d2 * 128 + sub * 8);
            bf16x8 h3 = *(const bf16x8*)(nfbf + (size_t)d3 * 128 + sub * 8);
            sev += ev0 + ev1 + ev2 + ev3;
#pragma unroll
            for (int i = 0; i < 8; i++) {
                acc[i] = fmaf(ev0, bf2f((unsigned short)h0[i]), acc[i]);
                acc[i] = fmaf(ev1, bf2f((unsigned short)h1[i]), acc[i]);
                acc[i] = fmaf(ev2, bf2f((unsigned short)h2[i]), acc[i]);
                acc[i] = fmaf(ev3, bf2f((unsigned short)h3[i]), acc[i]);
            }
        }
        for (; p < p1; p++) {
            int d = cdst[p];
            float ev = ebufC[p];
            bf16x8 hv = *(const bf16x8*)(nfbf + (size_t)d * 128 + sub * 8);
            sev += ev;
#pragma unroll
            for (int i = 0; i < 8; i++) acc[i] = fmaf(ev, bf2f((unsigned short)hv[i]), acc[i]);
        }
        float inv = 1.0f / (sev + 1e-16f);
#pragma unroll
        for (int i = 0; i < 8; i++) T[r16][sub * 8 + i] = acc[i] * inv;
    }
    __syncthreads();
    int w = tid >> 6, lane = tid & 63, lr = lane & 15, lg = lane >> 4;
    int col0 = w * 32 + lr, col1 = col0 + 16;
    int j = tid & 127, half = tid >> 7;
    {
        bf16x8 ahi[4], alo[4];
#pragma unroll
        for (int k = 0; k < 4; k++) mk_split(&T[lr][k * 32 + lg * 8], ahi[k], alo[k]);
        const unsigned short* wh0 = Whi + (size_t)col0 * 128 + lg * 8;
        const unsigned short* wl0 = Wlo + (size_t)col0 * 128 + lg * 8;
        const unsigned short* wh1 = Whi + (size_t)col1 * 128 + lg * 8;
        const unsigned short* wl1 = Wlo + (size_t)col1 * 128 + lg * 8;
        f32x4 a0 = {0.f, 0.f, 0.f, 0.f}, a1 = {0.f, 0.f, 0.f, 0.f};
#pragma unroll
        for (int k = 0; k < 4; k++) {
            bf16x8 bh = *(const bf16x8*)(wh0 + k * 32), bl = *(const bf16x8*)(wl0 + k * 32);
            a0 = MFMA(ahi[k], bh, a0, 0, 0, 0);
            a0 = MFMA(alo[k], bh, a0, 0, 0, 0);
            a0 = MFMA(ahi[k], bl, a0, 0, 0, 0);
            bh = *(const bf16x8*)(wh1 + k * 32); bl = *(const bf16x8*)(wl1 + k * 32);
            a1 = MFMA(ahi[k], bh, a1, 0, 0, 0);
            a1 = MFMA(alo[k], bh, a1, 0, 0, 0);
            a1 = MFMA(ahi[k], bl, a1, 0, 0, 0);
        }
#pragma unroll
        for (int i = 0; i < 4; i++) {
            int r = lg * 4 + i;
            T2[r][col0] = a0[i] + ob_t[col0];
            T2[r][col1] = a1[i] + ob_t[col1];
        }
    }
    __syncthreads();
    {
        int gr = tid >> 4, l16 = tid & 15;
        float sm = 0.0f, sq = 0.0f;
#pragma unroll
        for (int i = 0; i < 8; i++) {
            float v = T2[gr][l16 + 16 * i];
            sm += v; sq += v * v;
        }
#pragma unroll
        for (int m = 1; m < 16; m <<= 1) { sm += __shfl_xor(sm, m); sq += __shfl_xor(sq, m); }
        if (l16 == 0) {
            float mean = sm * (1.0f / 128.0f);
            float var = sq * (1.0f / 128.0f) - mean * mean;
            mu16[gr] = mean;
            rs16[gr] = rsqrtf(var + 1e-5f);
        }
    }
    __syncthreads();
    {
        float gj = g_t[j], bb = bln_t[j];
#pragma unroll
        for (int r = 0; r < 8; r++) {
            int rr = half * 8 + r;
            float v = fmaxf((T2[rr][j] - mu16[rr]) * rs16[rr] * gj + bb, 0.0f);
            emb[(row0 + rr) * 128 + j] = v;
            T2[rr][j] = v;
        }
    }
    __syncthreads();
    {
        bf16x8 ah[4];
#pragma unroll
        for (int k = 0; k < 4; k++) ah[k] = mk_hi(&T2[lr][k * 32 + lg * 8]);
        const unsigned short* wh0 = Shi + (size_t)col0 * 128 + lg * 8;
        const unsigned short* wh1 = Shi + (size_t)col1 * 128 + lg * 8;
        f32x4 a0 = {0.f, 0.f, 0.f, 0.f}, a1 = {0.f, 0.f, 0.f, 0.f};
#pragma unroll
        for (int k = 0; k < 4; k++) {
            a0 = MFMA(ah[k], *(const bf16x8*)(wh0 + k * 32), a0, 0, 0, 0);
            a1 = MFMA(ah[k], *(const bf16x8*)(wh1 + k * 32), a1, 0, 0, 0);
        }
        float b0 = sb1[col0], b1v = sb1[col1], w20 = sW2[col0], w21 = sW2[col1];
#pragma unroll
        for (int i = 0; i < 4; i++) {
            int r = lg * 4 + i;
            float v = tanhf_fast(a0[i] + b0) * w20 + tanhf_fast(a1[i] + b1v) * w21;
            v += __shfl_xor(v, 1);
            v += __shfl_xor(v, 2);
            v += __shfl_xor(v, 4);
            v += __shfl_xor(v, 8);
            if (lr == 0) part[w][r] = v;
        }
    }
    __syncthreads();
    if (tid < 16)
        scores[(row0 + tid) * 2 + t] = part[0][tid] + part[1][tid] + part[2][tid] + part[3][tid] + eb2[t];
}

// ---------------- TAIL-B1 ----------------
__global__ __launch_bounds__(256) void k_tailB1(const float* __restrict__ emb0,
                                                const float* __restrict__ emb1,
                                                const float* __restrict__ scores,
                                                const unsigned short* __restrict__ Fhi,
                                                const unsigned short* __restrict__ Flo,
                                                const float* __restrict__ eob,
                                                const float* __restrict__ elg,
                                                const float* __restrict__ elb,
                                                float* __restrict__ fused2) {
    __shared__ __align__(16) float T[16][132];
    __shared__ __align__(16) float T2[16][132];
    __shared__ float mu16[16], rs16[16], w0s[16], w1s[16];
    int tid = threadIdx.x;
    long row0 = (long)blockIdx.x * 16;
    if (tid < 16) {
        long r = row0 + tid;
        float s0 = scores[r * 2], s1 = scores[r * 2 + 1];
        float mx = fmaxf(s0, s1);
        float e0 = __expf(s0 - mx), e1 = __expf(s1 - mx);
        float inv = 1.0f / (e0 + e1);
        w0s[tid] = e0 * inv;
        w1s[tid] = e1 * inv;
    }
    __syncthreads();
#pragma unroll
    for (int i = 0; i < 8; i++) {
        int idx = tid + i * 256;
        int r = idx >> 7, c = idx & 127;
        T[r][c] = w0s[r] * emb0[(row0 + r) * 128 + c] + w1s[r] * emb1[(row0 + r) * 128 + c];
    }
    __syncthreads();
    int w = tid >> 6, lane = tid & 63, lr = lane & 15, lg = lane >> 4;
    int col0 = w * 32 + lr, col1 = col0 + 16;
    int j = tid & 127, half = tid >> 7;
    {
        bf16x8 ahi[4], alo[4];
#pragma unroll
        for (int k = 0; k < 4; k++) mk_split(&T[lr][k * 32 + lg * 8], ahi[k], alo[k]);
        const unsigned short* wh0 = Fhi + (size_t)col0 * 128 + lg * 8;
        const unsigned short* wl0 = Flo + (size_t)col0 * 128 + lg * 8;
        const unsigned short* wh1 = Fhi + (size_t)col1 * 128 + lg * 8;
        const unsigned short* wl1 = Flo + (size_t)col1 * 128 + lg * 8;
        f32x4 a0 = {0.f, 0.f, 0.f, 0.f}, a1 = {0.f, 0.f, 0.f, 0.f};
#pragma unroll
        for (int k = 0; k < 4; k++) {
            bf16x8 bh = *(const bf16x8*)(wh0 + k * 32), bl = *(const bf16x8*)(wl0 + k * 32);
            a0 = MFMA(ahi[k], bh, a0, 0, 0, 0);
            a0 = MFMA(alo[k], bh, a0, 0, 0, 0);
            a0 = MFMA(ahi[k], bl, a0, 0, 0, 0);
            bh = *(const bf16x8*)(wh1 + k * 32); bl = *(const bf16x8*)(wl1 + k * 32);
            a1 = MFMA(ahi[k], bh, a1, 0, 0, 0);
            a1 = MFMA(alo[k], bh, a1, 0, 0, 0);
            a1 = MFMA(ahi[k], bl, a1, 0, 0, 0);
        }
#pragma unroll
        for (int i = 0; i < 4; i++) {
            int r = lg * 4 + i;
            T2[r][col0] = a0[i] + eob[col0];
            T2[r][col1] = a1[i] + eob[col1];
        }
    }
    __syncthreads();
    {
        int gr = tid >> 4, l16 = tid & 15;
        float sm = 0.0f, sq = 0.0f;
#pragma unroll
        for (int i = 0; i < 8; i++) {
            float v = T2[gr][l16 + 16 * i];
            sm += v; sq += v * v;
        }
#pragma unroll
        for (int m = 1; m < 16; m <<= 1) { sm += __shfl_xor(sm, m); sq += __shfl_xor(sq, m); }
        if (l16 == 0) {
            float mean = sm * (1.0f / 128.0f);
            float var = sq * (1.0f / 128.0f) - mean * mean;
            mu16[gr] = mean;
            rs16[gr] = rsqrtf(var + 1e-5f);
        }
    }
    __syncthreads();
    {
        float gj = elg[j], bb = elb[j];
#pragma unroll
        for (int r = 0; r < 8; r++) {
            int rr = half * 8 + r;
            float v = fmaxf((T2[rr][j] - mu16[rr]) * rs16[rr] * gj + bb, 0.0f);
            fused2[(row0 + rr) * 128 + j] = v;
        }
    }
}

// ---------------- FSUM ----------------
__global__ __launch_bounds__(256) void k_fsum(const float* __restrict__ fused2,
                                              const int* __restrict__ lev,
                                              float* __restrict__ fsumg) {
    __shared__ float ls[2][4][128];
    int tid = threadIdx.x, half = tid >> 7, j = tid & 127;
#pragma unroll
    for (int l = 0; l < 4; l++) ls[half][l][j] = 0.0f;
    __syncthreads();
    for (long row = (long)blockIdx.x * 2 + half; row < NN; row += (long)gridDim.x * 2) {
        int l = lev[row];
        ls[half][l][j] += fused2[row * 128 + j];
    }
    __syncthreads();
    if (half == 0) {
#pragma unroll
        for (int l = 0; l < 4; l++) atomicAdd(&fsumg[l * 128 + j], ls[0][l][j] + ls[1][l][j]);
    }
}

// ---------------- FIN2 ----------------
__global__ void k_fin2(const float* __restrict__ fsum, const int* __restrict__ cnt4,
                       const float* __restrict__ hpW, const float* __restrict__ hpb,
                       const float* __restrict__ W1b, const float* __restrict__ b1,
                       float* __restrict__ lmean, float* __restrict__ lmw) {
    __shared__ float fs[128];
    __shared__ float lml[128];
    int l = blockIdx.x, j = threadIdx.x;
    fs[j] = fsum[l * 128 + j];
    __syncthreads();
    float c = (float)cnt4[l];
    float a = c * hpb[l * 128 + j];
    const float* wp = hpW + (size_t)l * 16384;
    for (int k = 0; k < 128; k++) a = fmaf(fs[k], wp[k * 128 + j], a);
    float cm = c < 1.0f ? 1.0f : c;
    float v = a / cm;
    lmean[l * 128 + j] = v;
    lml[j] = v;
    __syncthreads();
    float b = b1[j];
    for (int k = 0; k < 128; k++) b = fmaf(lml[k], W1b[k * 128 + j], b);
    lmw[l * 128 + j] = b;
}

// ---------------- TAIL-CD2 (level-bucketed) ----------------
__global__ __launch_bounds__(256) void k_tailCD2(const float* __restrict__ fused2,
                                                 const int* __restrict__ perm,
                                                 const int* __restrict__ cnt4,
                                                 const int* __restrict__ off4,
                                                 const int* __restrict__ boff5,
                                                 const unsigned short* __restrict__ QWhi,
                                                 const unsigned short* __restrict__ QWlo,
                                                 const float* __restrict__ qb,
                                                 const float* __restrict__ lmw,
                                                 const float* __restrict__ lmean,
                                                 const float* __restrict__ hW2,
                                                 const unsigned short* __restrict__ Ohi,
                                                 const unsigned short* __restrict__ Olo,
                                                 const float* __restrict__ hob,
                                                 const float* __restrict__ hlg,
                                                 const float* __restrict__ hlb,
                                                 float* __restrict__ out) {
    __shared__ __align__(16) float T[16][132];
    __shared__ __align__(16) float T2[16][132];
    __shared__ float lm[4][128];
    __shared__ float lmwS[4][128];
    __shared__ float w2S[128];
    __shared__ float scS[16][4];
    __shared__ float aw[16][4];
    __shared__ float mu16[16], rs16[16];
    __shared__ int idx16[16];
    int tid = threadIdx.x;
    int b = blockIdx.x;
    if (b >= boff5[4]) return;
    int l = (b >= boff5[3]) ? 3 : (b >= boff5[2]) ? 2 : (b >= boff5[1]) ? 1 : 0;
    int bi = b - boff5[l];
    int base = off4[l] + bi * 16;
    int last = off4[l] + cnt4[l] - 1;
    if (tid < 16) {
        int gp = base + tid;
        if (gp > last) gp = last;
        idx16[tid] = perm[gp];
    }
    for (int idx = tid; idx < 512; idx += 256) {
        lm[idx >> 7][idx & 127] = lmean[idx];
        lmwS[idx >> 7][idx & 127] = lmw[idx];
    }
    if (tid < 128) w2S[tid] = hW2[tid];
    __syncthreads();
#pragma unroll
    for (int i = 0; i < 8; i++) {
        int idx = tid + i * 256;
        int r = idx >> 7, c = idx & 127;
        T[r][c] = fused2[(size_t)idx16[r] * 128 + c];
    }
    __syncthreads();
    int w = tid >> 6, lane = tid & 63, lr = lane & 15, lg = lane >> 4;
    int col0 = w * 32 + lr, col1 = col0 + 16;
    int j = tid & 127, half = tid >> 7;
    {
        bf16x8 ahi[4], alo[4];
#pragma unroll
        for (int k = 0; k < 4; k++) mk_split(&T[lr][k * 32 + lg * 8], ahi[k], alo[k]);
        const unsigned short* wh0 = QWhi + (size_t)l * 16384 + (size_t)col0 * 128 + lg * 8;
        const unsigned short* wl0 = QWlo + (size_t)l * 16384 + (size_t)col0 * 128 + lg * 8;
        const unsigned short* wh1 = QWhi + (size_t)l * 16384 + (size_t)col1 * 128 + lg * 8;
        const unsigned short* wl1 = QWlo + (size_t)l * 16384 + (size_t)col1 * 128 + lg * 8;
        f32x4 a0 = {0.f, 0.f, 0.f, 0.f}, a1 = {0.f, 0.f, 0.f, 0.f};
#pragma unroll
        for (int k = 0; k < 4; k++) {
            bf16x8 bh = *(const bf16x8*)(wh0 + k * 32), bl = *(const bf16x8*)(wl0 + k * 32);
            a0 = MFMA(ahi[k], bh, a0, 0, 0, 0);
            a0 = MFMA(alo[k], bh, a0, 0, 0, 0);
            a0 = MFMA(ahi[k], bl, a0, 0, 0, 0);
            bh = *(const bf16x8*)(wh1 + k * 32); bl = *(const bf16x8*)(wl1 + k * 32);
            a1 = MFMA(ahi[k], bh, a1, 0, 0, 0);
            a1 = MFMA(alo[k], bh, a1, 0, 0, 0);
            a1 = MFMA(ahi[k], bl, a1, 0, 0, 0);
        }
#pragma unroll
        for (int i = 0; i < 4; i++) {
            int r = lg * 4 + i;
            T2[r][col0] = a0[i] + qb[l * 128 + col0];
            T2[r][col1] = a1[i] + qb[l * 128 + col1];
        }
    }
    __syncthreads();
    {
        int p = tid >> 2, sub = tid & 3;
        int pr = p & 15, pl = p >> 4;
        float s = 0.0f;
#pragma unroll
        for (int jj = 0; jj < 32; jj++) {
            int j2 = sub + 4 * jj;
            s += tanhf_fast(T2[pr][j2] + lmwS[pl][j2]) * w2S[j2];
        }
        s += __shfl_xor(s, 1);
        s += __shfl_xor(s, 2);
        if (sub == 0) scS[pr][pl] = s;
    }
    __syncthreads();
    if (tid < 16) {
        float sc[4];
        float mx = -1e30f;
#pragma unroll
        for (int ll = 0; ll < 4; ll++) {
            sc[ll] = scS[tid][ll];
            mx = fmaxf(mx, sc[ll]);
        }
        float s = 0.0f;
#pragma unroll
        for (int ll = 0; ll < 4; ll++) { sc[ll] = __expf(sc[ll] - mx); s += sc[ll]; }
        float inv = 1.0f / s;
#pragma unroll
        for (int ll = 0; ll < 4; ll++) aw[tid][ll] = sc[ll] * inv;
    }
    __syncthreads();
#pragma unroll
    for (int r = 0; r < 8; r++) {
        int rr = half * 8 + r;
        float e = 0.0f;
#pragma unroll
        for (int ll = 0; ll < 4; ll++) e = fmaf(aw[rr][ll], lm[ll][j], e);
        T[rr][j] = e;
    }
    __syncthreads();
    {
        bf16x8 ahi[4], alo[4];
#pragma unroll
        for (int k = 0; k < 4; k++) mk_split(&T[lr][k * 32 + lg * 8], ahi[k], alo[k]);
        const unsigned short* wh0 = Ohi + (size_t)col0 * 128 + lg * 8;
        const unsigned short* wl0 = Olo + (size_t)col0 * 128 + lg * 8;
        const unsigned short* wh1 = Ohi + (size_t)col1 * 128 + lg * 8;
        const unsigned short* wl1 = Olo + (size_t)col1 * 128 + lg * 8;
        f32x4 a0 = {0.f, 0.f, 0.f, 0.f}, a1 = {0.f, 0.f, 0.f, 0.f};
#pragma unroll
        for (int k = 0; k < 4; k++) {
            bf16x8 bh = *(const bf16x8*)(wh0 + k * 32), bl = *(const bf16x8*)(wl0 + k * 32);
            a0 = MFMA(ahi[k], bh, a0, 0, 0, 0);
            a0 = MFMA(alo[k], bh, a0, 0, 0, 0);
            a0 = MFMA(ahi[k], bl, a0, 0, 0, 0);
            bh = *(const bf16x8*)(wh1 + k * 32); bl = *(const bf16x8*)(wl1 + k * 32);
            a1 = MFMA(ahi[k], bh, a1, 0, 0, 0);
            a1 = MFMA(alo[k], bh, a1, 0, 0, 0);
            a1 = MFMA(ahi[k], bl, a1, 0, 0, 0);
        }
#pragma unroll
        for (int i = 0; i < 4; i++) {
            int r = lg * 4 + i;
            T2[r][col0] = a0[i] + hob[col0];
            T2[r][col1] = a1[i] + hob[col1];
        }
    }
    __syncthreads();
    {
        int gr = tid >> 4, l16 = tid & 15;
        float sm = 0.0f, sq = 0.0f;
#pragma unroll
        for (int i = 0; i < 8; i++) {
            float v = T2[gr][l16 + 16 * i];
            sm += v; sq += v * v;
        }
#pragma unroll
        for (int m = 1; m < 16; m <<= 1) { sm += __shfl_xor(sm, m); sq += __shfl_xor(sq, m); }
        if (l16 == 0) {
            float mean = sm * (1.0f / 128.0f);
            float var = sq * (1.0f / 128.0f) - mean * mean;
            mu16[gr] = mean;
            rs16[gr] = rsqrtf(var + 1e-5f);
        }
    }
    __syncthreads();
    {
        float gj = hlg[j], bb = hlb[j];
#pragma unroll
        for (int r = 0; r < 8; r++) {
            int rr = half * 8 + r;
            float v = (T2[rr][j] - mu16[rr]) * rs16[rr] * gj + bb;
            out[(size_t)idx16[rr] * 128 + j] = fmaxf(v, 0.0f);
        }
    }
}

extern "C" void kernel_launch(void* const* d_in, const int* in_sizes, int n_in,
                              void* d_out, int out_size, void* d_ws, size_t ws_size,
                              hipStream_t stream) {
    const float* nf  = (const float*)d_in[0];
    const float* ef  = (const float*)d_in[1];
    const int*   lev = (const int*)d_in[2];
    const int*   ei  = (const int*)d_in[3];
    const float* nlW = (const float*)d_in[4];
    const float* nlb = (const float*)d_in[5];
    const float* neW = (const float*)d_in[6];
    const float* neb = (const float*)d_in[7];
    const float* aW1 = (const float*)d_in[8];
    const float* ab1 = (const float*)d_in[9];
    const float* aW2 = (const float*)d_in[10];
    const float* ab2 = (const float*)d_in[11];
    const float* oW  = (const float*)d_in[12];
    const float* ob  = (const float*)d_in[13];
    const float* lng = (const float*)d_in[14];
    const float* lnb = (const float*)d_in[15];
    const float* eW1 = (const float*)d_in[16];
    const float* eb1 = (const float*)d_in[17];
    const float* eW2 = (const float*)d_in[18];
    const float* eb2 = (const float*)d_in[19];
    const float* eoW = (const float*)d_in[20];
    const float* eob = (const float*)d_in[21];
    const float* elg = (const float*)d_in[22];
    const float* elb = (const float*)d_in[23];
    const float* hpW = (const float*)d_in[24];
    const float* hpb = (const float*)d_in[25];
    const float* hW1 = (const float*)d_in[26];
    const float* hb1 = (const float*)d_in[27];
    const float* hW2 = (const float*)d_in[28];
    const float* hb2 = (const float*)d_in[29];
    const float* hoW = (const float*)d_in[30];
    const float* hob = (const float*)d_in[31];
    const float* hlg = (const float*)d_in[32];
    const float* hlb = (const float*)d_in[33];

    float* ws = (float*)d_ws;
    size_t NH = (size_t)NN * 128;
    float* fused2 = ws;                       // NH
    float* emb0   = fused2 + NH;              // NH
    float* emb1   = emb0 + NH;                // NH
    float* ebuf2  = emb1 + NH;                // 2*EE (CSR order)
    float* scores = ebuf2 + 2 * (size_t)EE;   // 2*NN
    float* beff2  = scores + (size_t)2 * NN;  // 256
    float* fsum   = beff2 + 256;              // 512
    float* lmean  = fsum + 512;               // 512
    float* lmw    = lmean + 512;              // 512
    float* qb     = lmw + 512;                // 512
    float* obf    = qb + 512;                 // 256
    _Float16* U2  = (_Float16*)(obf + 256);               // 2*NH
    _Float16* V2  = U2 + 2 * NH;                          // 2*NH
    unsigned short* nfbf  = (unsigned short*)(V2 + 2 * NH); // NH
    unsigned short* WUT2  = nfbf + NH;                    // 2*16384
    unsigned short* WVT2  = WUT2 + 2 * 16384;
    unsigned short* WET2  = WVT2 + 2 * 16384;             // 2*8192
    unsigned short* twhi  = WET2 + 2 * 8192;              // 4*16384
    unsigned short* twlo  = twhi + 4 * 16384;             // 4*16384
    unsigned short* foldhi = twlo + 4 * 16384;            // 2*16384
    unsigned short* foldlo = foldhi + 2 * 16384;          // 2*16384
    unsigned short* QWhi  = foldlo + 2 * 16384;           // 4*16384
    unsigned short* QWlo  = QWhi + 4 * 16384;             // 4*16384
    int* perm    = (int*)(QWlo + 4 * 16384);              // NN
    int* cnt4    = perm + NN;
    int* off4    = cnt4 + 4;
    int* boff5   = off4 + 4;
    int* cursorL = boff5 + 5;
    int* deg2    = cursorL + 4;          // 2*NN
    int* rowptr2 = deg2 + 2 * NN;        // 2*NN+1
    int* cursor2 = rowptr2 + 2 * NN + 1; // 2*NN
    int* stmp    = cursor2 + 2 * NN;     // 2*NN
    int* sbsum   = stmp + 2 * NN;        // 512
    int* sboff   = sbsum + 512;          // 512
    int* ceid2   = sboff + 512;          // 2*EE
    int* cs2     = ceid2 + 2 * EE;       // 2*EE
    int* cdst2   = cs2 + 2 * EE;         // 2*EE
    float* out = (float*)d_out;

    WSrc ps;
    ps.s[0] = eW1;              // score W1 t0
    ps.s[1] = eW1 + 16384;      // score W1 t1
    ps.s[2] = eoW;
    ps.s[3] = hoW;

    const int NB_N = NN / 16;             // 6250
    const int SCB = (2 * NN + 511) / 512; // 391

    // level bucketing
    k_zeroi<<<1, 4, 0, stream>>>(cnt4, 4);
    k_count<<<128, 256, 0, stream>>>(lev, cnt4);
    k_scan<<<1, 1, 0, stream>>>(cnt4, off4, boff5, cursorL);
    k_scatter<<<125, 256, 0, stream>>>(lev, cursorL, perm);

    // weight prep
    k_prep_tail<<<4 * 64, 256, 0, stream>>>(ps, twhi, twlo);
    k_prep_fold<<<129, 256, 0, stream>>>(nlW, nlb, oW, ob, foldhi, foldlo, obf);
    k_prep_q<<<258, 256, 0, stream>>>(hpW, hpb, hW1, QWhi, QWlo, qb);
    k_zero<<<1, 512, 0, stream>>>(fsum, (size_t)512);

    // nf -> bf16 (shared gather source)
    k_nfcvt<<<NH_C / 8 / 256, 256, 0, stream>>>(nf, nfbf);

    // CSR build (both relations at once)
    k_zeroi<<<(2 * NN + 255) / 256, 256, 0, stream>>>(deg2, 2 * NN);
    k_hist2<<<(2 * EE + 255) / 256, 256, 0, stream>>>(ei, deg2);
    k_scan1<<<SCB, 512, 0, stream>>>(deg2, stmp, sbsum);
    k_scan2<<<1, 512, 0, stream>>>(sbsum, sboff, SCB);
    k_scan3<<<SCB, 512, 0, stream>>>(deg2, stmp, sboff, rowptr2, cursor2);
    k_csr_scatter3<<<(2 * EE + 255) / 256, 256, 0, stream>>>(ei, cursor2, ceid2, cs2, cdst2);

    // head (both t, one nf pass): U,V in fp16
    k_prep_head2<<<256, 128, 0, stream>>>(nlW, nlb, aW1, ab1, neW, neb,
                                          WUT2, WVT2, WET2, beff2);
    k_head2c<<<NB_N, 256, 0, stream>>>(nf, WUT2, WVT2, U2, V2);

    // edge scores (CSR order, both t)
    k_edge6<<<2 * EE / EBLK, 256, 0, stream>>>(ef, ceid2, cs2, cdst2, WET2, U2, V2,
                                               beff2, aW2, ab2, ebuf2);
    // aggregation (nfbf gather) + folded GEMM + relation tail (both t)
    k_tailA2c<<<2 * NB_N, 256, 0, stream>>>(rowptr2, cdst2, ebuf2, nfbf,
                                            foldhi, foldlo, twhi, obf,
                                            lng, lnb, eb1, eW2, eb2,
                                            emb0, emb1, scores, NB_N);

    k_tailB1<<<NB_N, 256, 0, stream>>>(emb0, emb1, scores,
                                       twhi + (size_t)2 * 16384, twlo + (size_t)2 * 16384,
                                       eob, elg, elb, fused2);
    k_fsum<<<256, 256, 0, stream>>>(fused2, lev, fsum);
    k_fin2<<<4, 128, 0, stream>>>(fsum, cnt4, hpW, hpb, hW1 + 16384, hb1, lmean, lmw);
    k_tailCD2<<<NB_N + 4, 256, 0, stream>>>(fused2, perm, cnt4, off4, boff5,
                                            QWhi, QWlo, qb, lmw, lmean, hW2,
                                            twhi + (size_t)3 * 16384, twlo + (size_t)3 * 16384,
                                            hob, hlg, hlb, out);
}

// Round 16
// 904.881 us; speedup vs baseline: 1.0086x; 1.0086x over previous
//
#include <hip/hip_runtime.h>
#include <math.h>

#define NN 100000
#define EE 500000
#define NH_C (NN * 128)
#define EBLK 32
// D=H=128, ED=64, T=2, L=4

typedef __attribute__((ext_vector_type(8))) short bf16x8;
typedef __attribute__((ext_vector_type(4))) float f32x4;
#define MFMA __builtin_amdgcn_mfma_f32_16x16x32_bf16

__device__ inline short f2bf(float x) {
    union { float f; unsigned u; } v; v.f = x;
    unsigned r = v.u + 0x7FFF + ((v.u >> 16) & 1);
    return (short)(r >> 16);
}
__device__ inline float bf2f(unsigned short h) {
    union { unsigned u; float f; } v; v.u = ((unsigned)h) << 16; return v.f;
}
__device__ inline float tanhf_fast(float x) {
    float e = __expf(2.0f * x);
    return 1.0f - 2.0f * __builtin_amdgcn_rcpf(e + 1.0f);
}

__device__ inline bf16x8 mk_hi(const float* p) {
    float4 a = *(const float4*)p, b = *(const float4*)(p + 4);
    float v[8] = {a.x, a.y, a.z, a.w, b.x, b.y, b.z, b.w};
    bf16x8 h;
#pragma unroll
    for (int i = 0; i < 8; i++) h[i] = f2bf(v[i]);
    return h;
}
__device__ inline bf16x8 mk_hi8(float4 a, float4 b) {
    float v[8] = {a.x, a.y, a.z, a.w, b.x, b.y, b.z, b.w};
    bf16x8 h;
#pragma unroll
    for (int i = 0; i < 8; i++) h[i] = f2bf(v[i]);
    return h;
}
__device__ inline void mk_split(const float* p, bf16x8& hi, bf16x8& lo) {
    float4 a = *(const float4*)p, b = *(const float4*)(p + 4);
    float v[8] = {a.x, a.y, a.z, a.w, b.x, b.y, b.z, b.w};
#pragma unroll
    for (int i = 0; i < 8; i++) {
        short h = f2bf(v[i]);
        hi[i] = h;
        lo[i] = f2bf(v[i] - bf2f((unsigned short)h));
    }
}

// ---------------- zero fill ----------------
__global__ void k_zero(float* __restrict__ p, size_t n) {
    size_t i = (size_t)blockIdx.x * blockDim.x + threadIdx.x;
    size_t stride = (size_t)gridDim.x * blockDim.x;
    for (; i < n; i += stride) p[i] = 0.0f;
}
__global__ void k_zeroi(int* __restrict__ p, int n) {
    int i = blockIdx.x * blockDim.x + threadIdx.x;
    if (i < n) p[i] = 0;
}

// ---------------- nf -> bf16 (shared across both relations) ----------------
__global__ __launch_bounds__(256) void k_nfcvt(const float* __restrict__ nf,
                                               unsigned short* __restrict__ nfbf) {
    long gid = (long)blockIdx.x * 256 + threadIdx.x;
    if (gid >= (long)NH_C / 8) return;
    const float* sp = nf + gid * 8;
    f32x4 a = *(const f32x4*)sp;
    f32x4 b = *(const f32x4*)(sp + 4);
    bf16x8 h;
    h[0] = f2bf(a[0]); h[1] = f2bf(a[1]); h[2] = f2bf(a[2]); h[3] = f2bf(a[3]);
    h[4] = f2bf(b[0]); h[5] = f2bf(b[1]); h[6] = f2bf(b[2]); h[7] = f2bf(b[3]);
    *(bf16x8*)(nfbf + gid * 8) = h;
}

// ---------------- CSR build (both relations, concatenated) ----------------
__global__ __launch_bounds__(256) void k_hist2(const int* __restrict__ ei, int* __restrict__ deg2) {
    long g = (long)blockIdx.x * 256 + threadIdx.x;
    if (g < 2L * EE) {
        int t = g >= EE;
        long le = g - (long)t * EE;
        int s = ei[(size_t)t * 2 * EE + le];
        atomicAdd(&deg2[t * NN + s], 1);
    }
}
__global__ __launch_bounds__(512) void k_scan1(const int* __restrict__ deg,
                                               int* __restrict__ tmp, int* __restrict__ bsum) {
    __shared__ int sh[2][512];
    int b = blockIdx.x, tid = threadIdx.x;
    int i = b * 512 + tid;
    int v = (i < 2 * NN) ? deg[i] : 0;
    int cur = 0;
    sh[0][tid] = v;
    __syncthreads();
    for (int off = 1; off < 512; off <<= 1) {
        int nxt = cur ^ 1;
        int a = sh[cur][tid];
        if (tid >= off) a += sh[cur][tid - off];
        sh[nxt][tid] = a;
        __syncthreads();
        cur = nxt;
    }
    int incl = sh[cur][tid];
    if (i < 2 * NN) tmp[i] = incl;
    if (tid == 511) bsum[b] = incl;
}
__global__ __launch_bounds__(512) void k_scan2(const int* __restrict__ bsum, int* __restrict__ boff,
                                               int nB) {
    __shared__ int sh[2][512];
    int tid = threadIdx.x;
    int v = (tid < nB) ? bsum[tid] : 0;
    int cur = 0;
    sh[0][tid] = v;
    __syncthreads();
    for (int off = 1; off < 512; off <<= 1) {
        int nxt = cur ^ 1;
        int a = sh[cur][tid];
        if (tid >= off) a += sh[cur][tid - off];
        sh[nxt][tid] = a;
        __syncthreads();
        cur = nxt;
    }
    boff[tid] = sh[cur][tid] - v;
}
__global__ __launch_bounds__(512) void k_scan3(const int* __restrict__ deg,
                                               const int* __restrict__ tmp,
                                               const int* __restrict__ boff,
                                               int* __restrict__ rowptr, int* __restrict__ cursor) {
    int i = blockIdx.x * 512 + threadIdx.x;
    if (i < 2 * NN) {
        int r = tmp[i] - deg[i] + boff[blockIdx.x];
        rowptr[i] = r;
        cursor[i] = r;
    }
    if (i == 0) rowptr[2 * NN] = 2 * EE;
}
__global__ __launch_bounds__(256) void k_csr_scatter3(const int* __restrict__ ei,
                                                      int* __restrict__ cursor,
                                                      int* __restrict__ ceid,
                                                      int* __restrict__ cs,
                                                      int* __restrict__ cdst) {
    long g = (long)blockIdx.x * 256 + threadIdx.x;
    if (g < 2L * EE) {
        int t = g >= EE;
        long le = g - (long)t * EE;
        int s = ei[(size_t)t * 2 * EE + le];
        int d = ei[(size_t)t * 2 * EE + EE + le];
        int p = atomicAdd(&cursor[t * NN + s], 1);
        ceid[p] = (int)le;
        cs[p] = s;
        cdst[p] = d;
    }
}

// ---------------- level bucketing ----------------
__global__ __launch_bounds__(256) void k_count(const int* __restrict__ lev, int* __restrict__ cnt4) {
    __shared__ int lc[4];
    int tid = threadIdx.x;
    if (tid < 4) lc[tid] = 0;
    __syncthreads();
    for (long n = (long)blockIdx.x * 256 + tid; n < NN; n += (long)gridDim.x * 256)
        atomicAdd(&lc[lev[n]], 1);
    __syncthreads();
    if (tid < 4 && lc[tid]) atomicAdd(&cnt4[tid], lc[tid]);
}

__global__ void k_scan(const int* __restrict__ cnt4, int* __restrict__ off4,
                       int* __restrict__ boff5, int* __restrict__ cursor) {
    int o = 0, b = 0;
    for (int l = 0; l < 4; l++) {
        off4[l] = o; cursor[l] = o; boff5[l] = b;
        o += cnt4[l];
        b += (cnt4[l] + 15) >> 4;
    }
    boff5[4] = b;
}

__global__ __launch_bounds__(256) void k_scatter(const int* __restrict__ lev,
                                                 int* __restrict__ cursor,
                                                 int* __restrict__ perm) {
    __shared__ int lc[4], lb[4], lc2[4];
    int tid = threadIdx.x;
    if (tid < 4) { lc[tid] = 0; lc2[tid] = 0; }
    __syncthreads();
    int start = blockIdx.x * 800, end = start + 800;
    if (end > NN) end = NN;
    for (int n = start + tid; n < end; n += 256) atomicAdd(&lc[lev[n]], 1);
    __syncthreads();
    if (tid < 4 && lc[tid]) lb[tid] = atomicAdd(&cursor[tid], lc[tid]);
    __syncthreads();
    for (int n = start + tid; n < end; n += 256) {
        int l = lev[n];
        int p = atomicAdd(&lc2[l], 1);
        perm[lb[l] + p] = n;
    }
}

// ---------------- prep head (both t): WUT2, WVT2, WET2 (bf16 T), beff2 ----------------
__global__ void k_prep_head2(const float* __restrict__ nlW, const float* __restrict__ nlb,
                             const float* __restrict__ aW1, const float* __restrict__ ab1,
                             const float* __restrict__ neW, const float* __restrict__ neb,
                             unsigned short* __restrict__ WUT2,
                             unsigned short* __restrict__ WVT2, unsigned short* __restrict__ WET2,
                             float* __restrict__ beff2) {
    __shared__ float red[2];
    int t = blockIdx.x >> 7, j = blockIdx.x & 127, k = threadIdx.x;
    const float* Wn = nlW + (size_t)t * 16384;
    const float* bn = nlb + t * 128;
    const float* W1 = aW1 + (size_t)t * 384 * 128;
    const float* b1 = ab1 + t * 128;
    const float* We = neW + (size_t)t * 64 * 128;
    const float* be = neb + t * 128;
    float su = 0.0f, sv = 0.0f;
    for (int m = 0; m < 128; m++) {
        float wkm = Wn[k * 128 + m];
        su = fmaf(wkm, W1[m * 128 + j], su);
        sv = fmaf(wkm, W1[(128 + m) * 128 + j], sv);
    }
    WUT2[(size_t)t * 16384 + j * 128 + k] = (unsigned short)f2bf(su);
    WVT2[(size_t)t * 16384 + j * 128 + k] = (unsigned short)f2bf(sv);
    if (k < 64) {
        float se = 0.0f;
        for (int m = 0; m < 128; m++) se = fmaf(We[k * 128 + m], W1[(256 + m) * 128 + j], se);
        WET2[(size_t)t * 8192 + j * 64 + k] = (unsigned short)f2bf(se);
    }
    float tk = bn[k] * (W1[k * 128 + j] + W1[(128 + k) * 128 + j]) + be[k] * W1[(256 + k) * 128 + j];
#pragma unroll
    for (int o = 32; o > 0; o >>= 1) tk += __shfl_down(tk, o);
    if ((k & 63) == 0) red[k >> 6] = tk;
    __syncthreads();
    if (k == 0) beff2[t * 128 + j] = b1[j] + red[0] + red[1];
}

// ---------------- prep tail: split-bf16 transposed weights (4 mats) ----------------
struct WSrc { const float* s[4]; };
__global__ void k_prep_tail(WSrc ps, unsigned short* __restrict__ hi,
                            unsigned short* __restrict__ lo) {
    int m = blockIdx.x >> 6, blk = blockIdx.x & 63;
    const float* src = ps.s[m];
    unsigned short* h = hi + (size_t)m * 16384;
    unsigned short* l = lo + (size_t)m * 16384;
    int idx = blk * 256 + threadIdx.x;
    int k = idx >> 7, j = idx & 127;
    float v = src[idx];
    short hh = f2bf(v);
    h[j * 128 + k] = (unsigned short)hh;
    l[j * 128 + k] = (unsigned short)f2bf(v - bf2f((unsigned short)hh));
}

// ---------------- prep fold: oWf[t] = Wn[t]@oW[t] (T split bf16); obf = bn@oW + ob ----------
__global__ void k_prep_fold(const float* __restrict__ nlW, const float* __restrict__ nlb,
                            const float* __restrict__ oW, const float* __restrict__ ob,
                            unsigned short* __restrict__ foldhi, unsigned short* __restrict__ foldlo,
                            float* __restrict__ obf) {
    int gidx = blockIdx.x * 256 + threadIdx.x;
    if (gidx < 2 * 16384) {
        int t = gidx >> 14, rem = gidx & 16383;
        int k = rem >> 7, j = rem & 127;
        const float* wn = nlW + (size_t)t * 16384 + (size_t)k * 128;
        const float* ow = oW + (size_t)t * 16384;
        float v = 0.0f;
        for (int m = 0; m < 128; m++) v = fmaf(wn[m], ow[m * 128 + j], v);
        short hh = f2bf(v);
        foldhi[(size_t)t * 16384 + j * 128 + k] = (unsigned short)hh;
        foldlo[(size_t)t * 16384 + j * 128 + k] = (unsigned short)f2bf(v - bf2f((unsigned short)hh));
    } else {
        int e = gidx - 2 * 16384;
        if (e < 256) {
            int t = e >> 7, j = e & 127;
            float v = ob[t * 128 + j];
            for (int m = 0; m < 128; m++)
                v = fmaf(nlb[t * 128 + m], oW[(size_t)t * 16384 + m * 128 + j], v);
            obf[t * 128 + j] = v;
        }
    }
}

// ---------------- prep Q: QW[l] = hpW[l] @ hW1a (T split bf16), qb[l] = hpb[l]@hW1a ----------
__global__ void k_prep_q(const float* __restrict__ hpW, const float* __restrict__ hpb,
                         const float* __restrict__ hW1a,
                         unsigned short* __restrict__ QWhi, unsigned short* __restrict__ QWlo,
                         float* __restrict__ qb) {
    int gidx = blockIdx.x * 256 + threadIdx.x;
    if (gidx < 4 * 16384) {
        int l = gidx >> 14, rem = gidx & 16383;
        int k = rem >> 7, j = rem & 127;
        const float* wr = hpW + (size_t)l * 16384 + (size_t)k * 128;
        float v = 0.0f;
        for (int m = 0; m < 128; m++) v = fmaf(wr[m], hW1a[m * 128 + j], v);
        short hh = f2bf(v);
        QWhi[(size_t)l * 16384 + j * 128 + k] = (unsigned short)hh;
        QWlo[(size_t)l * 16384 + j * 128 + k] = (unsigned short)f2bf(v - bf2f((unsigned short)hh));
    } else {
        int e = gidx - 4 * 16384;
        if (e < 512) {
            int l = e >> 7, j = e & 127;
            float v = 0.0f;
            for (int m = 0; m < 128; m++) v = fmaf(hpb[l * 128 + m], hW1a[m * 128 + j], v);
            qb[l * 128 + j] = v;
        }
    }
}

// ---------------- HEAD2B: both t from one nf tile -> U,V (x2) ----------------
__global__ __launch_bounds__(256) void k_head2b(const float* __restrict__ nf,
                                                const unsigned short* __restrict__ WUT2,
                                                const unsigned short* __restrict__ WVT2,
                                                unsigned short* __restrict__ U2,
                                                unsigned short* __restrict__ V2) {
    __shared__ __align__(16) float T[16][132];
    int tid = threadIdx.x;
    long row0 = (long)blockIdx.x * 16;
#pragma unroll
    for (int i = 0; i < 8; i++) {
        int idx = tid + i * 256;
        int r = idx >> 7, c = idx & 127;
        T[r][c] = nf[(row0 + r) * 128 + c];
    }
    __syncthreads();
    int w = tid >> 6, lane = tid & 63, lr = lane & 15, lg = lane >> 4;
    bf16x8 A[4];
#pragma unroll
    for (int k = 0; k < 4; k++) A[k] = mk_hi(&T[lr][k * 32 + lg * 8]);
    int col0 = w * 32 + lr, col1 = col0 + 16;
#pragma unroll
    for (int o = 0; o < 4; o++) {
        int t = o >> 1, uv = o & 1;
        const unsigned short* wb = (uv ? WVT2 : WUT2) + (size_t)t * 16384;
        unsigned short* ob = (uv ? V2 : U2) + (size_t)t * NH_C;
        const unsigned short* w0 = wb + (size_t)col0 * 128 + lg * 8;
        const unsigned short* w1 = wb + (size_t)col1 * 128 + lg * 8;
        f32x4 a0 = {0.f, 0.f, 0.f, 0.f}, a1 = {0.f, 0.f, 0.f, 0.f};
#pragma unroll
        for (int k = 0; k < 4; k++) {
            a0 = MFMA(A[k], *(const bf16x8*)(w0 + k * 32), a0, 0, 0, 0);
            a1 = MFMA(A[k], *(const bf16x8*)(w1 + k * 32), a1, 0, 0, 0);
        }
        unsigned short* op = ob + (size_t)row0 * 128;
#pragma unroll
        for (int i = 0; i < 4; i++) {
            int r = lg * 4 + i;
            op[(size_t)r * 128 + col0] = (unsigned short)f2bf(a0[i]);
            op[(size_t)r * 128 + col1] = (unsigned short)f2bf(a1[i]);
        }
    }
}

// ---------------- EDGE5 (CSR order, both t): U seq/L1-hot, V+ef gather, ev coalesced ----
__global__ __launch_bounds__(256) void k_edge5(const float* __restrict__ ef,
                                               const int* __restrict__ ceid,
                                               const int* __restrict__ cs,
                                               const int* __restrict__ cdst,
                                               const unsigned short* __restrict__ WET2,
                                               const unsigned short* __restrict__ U2,
                                               const unsigned short* __restrict__ V2,
                                               const float* __restrict__ beff2,
                                               const float* __restrict__ aW2,
                                               const float* __restrict__ ab2,
                                               float* __restrict__ ebuf2) {
    __shared__ __align__(16) float pre[EBLK][132];
    __shared__ float part[4][EBLK];
    __shared__ int eS[EBLK];
    int tid = threadIdx.x, w = tid >> 6, lane = tid & 63, lr = lane & 15, lg = lane >> 4;
    long p0 = (long)blockIdx.x * EBLK;
    int t = p0 >= (long)EE;
    const float* ef_t = ef + (size_t)t * EE * 64;
    const unsigned short* U_t = U2 + (size_t)t * NH_C;
    const unsigned short* V_t = V2 + (size_t)t * NH_C;
    {
        int eL = tid >> 3, sub = tid & 7;
        int uch = (sub + eL) & 7;
        long p = p0 + eL;
        int s = cs[p], d = cdst[p];
        const unsigned short* up = U_t + (size_t)s * 128 + uch * 16;
        const unsigned short* vp = V_t + (size_t)d * 128 + uch * 16;
        bf16x8 u0 = *(const bf16x8*)up, u1 = *(const bf16x8*)(up + 8);
        bf16x8 v0 = *(const bf16x8*)vp, v1 = *(const bf16x8*)(vp + 8);
        float tv[16];
#pragma unroll
        for (int i = 0; i < 8; i++)
            tv[i] = bf2f((unsigned short)u0[i]) + bf2f((unsigned short)v0[i]);
#pragma unroll
        for (int i = 0; i < 8; i++)
            tv[8 + i] = bf2f((unsigned short)u1[i]) + bf2f((unsigned short)v1[i]);
#pragma unroll
        for (int i = 0; i < 4; i++) {
            float4 f4 = {tv[4 * i], tv[4 * i + 1], tv[4 * i + 2], tv[4 * i + 3]};
            *(float4*)&pre[eL][uch * 16 + 4 * i] = f4;
        }
    }
    if (tid < EBLK) eS[tid] = ceid[p0 + tid];
    int col0 = w * 32 + lr, col1 = col0 + 16;
    bf16x8 B0[2], B1[2];
#pragma unroll
    for (int kk = 0; kk < 2; kk++) {
        B0[kk] = *(const bf16x8*)(WET2 + (size_t)t * 8192 + (size_t)col0 * 64 + kk * 32 + lg * 8);
        B1[kk] = *(const bf16x8*)(WET2 + (size_t)t * 8192 + (size_t)col1 * 64 + kk * 32 + lg * 8);
    }
    float be0 = beff2[t * 128 + col0], be1 = beff2[t * 128 + col1];
    float w20 = aW2[t * 128 + col0], w21 = aW2[t * 128 + col1];
    __syncthreads();
#pragma unroll
    for (int i16 = 0; i16 < 2; i16++) {
        int e = eS[i16 * 16 + lr];
        const float* ep = ef_t + (size_t)e * 64 + lg * 8;
        float4 L0 = *(const float4*)ep;
        float4 L1 = *(const float4*)(ep + 4);
        float4 L2 = *(const float4*)(ep + 32);
        float4 L3 = *(const float4*)(ep + 36);
        bf16x8 av0 = mk_hi8(L0, L1);
        bf16x8 av1 = mk_hi8(L2, L3);
        f32x4 a0 = {0.f, 0.f, 0.f, 0.f}, a1 = {0.f, 0.f, 0.f, 0.f};
        a0 = MFMA(av0, B0[0], a0, 0, 0, 0);
        a0 = MFMA(av1, B0[1], a0, 0, 0, 0);
        a1 = MFMA(av0, B1[0], a1, 0, 0, 0);
        a1 = MFMA(av1, B1[1], a1, 0, 0, 0);
#pragma unroll
        for (int q = 0; q < 4; q++) {
            int eL = i16 * 16 + lg * 4 + q;
            float v = tanhf_fast(a0[q] + pre[eL][col0] + be0) * w20 +
                      tanhf_fast(a1[q] + pre[eL][col1] + be1) * w21;
            v += __shfl_xor(v, 1);
            v += __shfl_xor(v, 2);
            v += __shfl_xor(v, 4);
            v += __shfl_xor(v, 8);
            if (lr == 0) part[w][eL] = v;
        }
    }
    __syncthreads();
    if (tid < EBLK) {
        float a = part[0][tid] + part[1][tid] + part[2][tid] + part[3][tid] + ab2[t];
        ebuf2[p0 + tid] = __expf(a);
    }
}

// ---------------- TAIL-A2C (both t): CSR gather of nfbf + folded GEMM + LN + score ---------
__global__ __launch_bounds__(256) void k_tailA2c(const int* __restrict__ rowptr2,
                                                 const int* __restrict__ cdst,
                                                 const float* __restrict__ ebufC,
                                                 const unsigned short* __restrict__ nfbf,
                                                 const unsigned short* __restrict__ foldhi,
                                                 const unsigned short* __restrict__ foldlo,
                                                 const unsigned short* __restrict__ twhi,
                                                 const float* __restrict__ obf,
                                                 const float* __restrict__ lng,
                                                 const float* __restrict__ lnb,
                                                 const float* __restrict__ eb1,
                                                 const float* __restrict__ eW2,
                                                 const float* __restrict__ eb2,
                                                 float* __restrict__ emb0,
                                                 float* __restrict__ emb1,
                                                 float* __restrict__ scores, int NBn) {
    __shared__ __align__(16) float T[16][132];
    __shared__ __align__(16) float T2[16][132];
    __shared__ float mu16[16], rs16[16], part[4][16];
    int tid = threadIdx.x;
    int t = blockIdx.x >= NBn;
    int bi = blockIdx.x - t * NBn;
    long row0 = (long)bi * 16;
    const int* rowp = rowptr2 + (size_t)t * NN;
    const unsigned short* Whi = foldhi + (size_t)t * 16384;
    const unsigned short* Wlo = foldlo + (size_t)t * 16384;
    const unsigned short* Shi = twhi + (size_t)t * 16384;
    const float* ob_t = obf + t * 128;
    const float* g_t = lng + t * 128;
    const float* bln_t = lnb + t * 128;
    const float* sb1 = eb1 + t * 128;
    const float* sW2 = eW2 + t * 128;
    float* emb = t ? emb1 : emb0;
    // CSR gather of nfbf (shared for both t): 16 threads/row, 4-way unrolled
    {
        int r16 = tid >> 4, sub = tid & 15;
        long n = row0 + r16;
        int p0 = rowp[n], p1 = rowp[n + 1];
        float acc[8] = {0, 0, 0, 0, 0, 0, 0, 0};
        float sev = 0.0f;
        int p = p0;
        for (; p + 4 <= p1; p += 4) {
            int d0 = cdst[p], d1 = cdst[p + 1], d2 = cdst[p + 2], d3 = cdst[p + 3];
            float ev0 = ebufC[p], ev1 = ebufC[p + 1];
            float ev2 = ebufC[p + 2], ev3 = ebufC[p + 3];
            bf16x8 h0 = *(const bf16x8*)(nfbf + (size_t)d0 * 128 + sub * 8);
            bf16x8 h1 = *(const bf16x8*)(nfbf + (size_t)d1 * 128 + sub * 8);
            bf16x8 h2 = *(const bf16x8*)(nfbf + (size_t)d2 * 128 + sub * 8);
            bf16x8 h3 = *(const bf16x8*)(nfbf + (size_t)d3 * 128 + sub * 8);
            sev += ev0 + ev1 + ev2 + ev3;
#pragma unroll
            for (int i = 0; i < 8; i++) {
                acc[i] = fmaf(ev0, bf2f((unsigned short)h0[i]), acc[i]);
                acc[i] = fmaf(ev1, bf2f((unsigned short)h1[i]), acc[i]);
                acc[i] = fmaf(ev2, bf2f((unsigned short)h2[i]), acc[i]);
                acc[i] = fmaf(ev3, bf2f((unsigned short)h3[i]), acc[i]);
            }
        }
        for (; p < p1; p++) {
            int d = cdst[p];
            float ev = ebufC[p];
            bf16x8 hv = *(const bf16x8*)(nfbf + (size_t)d * 128 + sub * 8);
            sev += ev;
#pragma unroll
            for (int i = 0; i < 8; i++) acc[i] = fmaf(ev, bf2f((unsigned short)hv[i]), acc[i]);
        }
        float inv = 1.0f / (sev + 1e-16f);
#pragma unroll
        for (int i = 0; i < 8; i++) T[r16][sub * 8 + i] = acc[i] * inv;
    }
    __syncthreads();
    int w = tid >> 6, lane = tid & 63, lr = lane & 15, lg = lane >> 4;
    int col0 = w * 32 + lr, col1 = col0 + 16;
    int j = tid & 127, half = tid >> 7;
    {
        bf16x8 ahi[4], alo[4];
#pragma unroll
        for (int k = 0; k < 4; k++) mk_split(&T[lr][k * 32 + lg * 8], ahi[k], alo[k]);
        const unsigned short* wh0 = Whi + (size_t)col0 * 128 + lg * 8;
        const unsigned short* wl0 = Wlo + (size_t)col0 * 128 + lg * 8;
        const unsigned short* wh1 = Whi + (size_t)col1 * 128 + lg * 8;
        const unsigned short* wl1 = Wlo + (size_t)col1 * 128 + lg * 8;
        f32x4 a0 = {0.f, 0.f, 0.f, 0.f}, a1 = {0.f, 0.f, 0.f, 0.f};
#pragma unroll
        for (int k = 0; k < 4; k++) {
            bf16x8 bh = *(const bf16x8*)(wh0 + k * 32), bl = *(const bf16x8*)(wl0 + k * 32);
            a0 = MFMA(ahi[k], bh, a0, 0, 0, 0);
            a0 = MFMA(alo[k], bh, a0, 0, 0, 0);
            a0 = MFMA(ahi[k], bl, a0, 0, 0, 0);
            bh = *(const bf16x8*)(wh1 + k * 32); bl = *(const bf16x8*)(wl1 + k * 32);
            a1 = MFMA(ahi[k], bh, a1, 0, 0, 0);
            a1 = MFMA(alo[k], bh, a1, 0, 0, 0);
            a1 = MFMA(ahi[k], bl, a1, 0, 0, 0);
        }
#pragma unroll
        for (int i = 0; i < 4; i++) {
            int r = lg * 4 + i;
            T2[r][col0] = a0[i] + ob_t[col0];
            T2[r][col1] = a1[i] + ob_t[col1];
        }
    }
    __syncthreads();
    {
        int gr = tid >> 4, l16 = tid & 15;
        float sm = 0.0f, sq = 0.0f;
#pragma unroll
        for (int i = 0; i < 8; i++) {
            float v = T2[gr][l16 + 16 * i];
            sm += v; sq += v * v;
        }
#pragma unroll
        for (int m = 1; m < 16; m <<= 1) { sm += __shfl_xor(sm, m); sq += __shfl_xor(sq, m); }
        if (l16 == 0) {
            float mean = sm * (1.0f / 128.0f);
            float var = sq * (1.0f / 128.0f) - mean * mean;
            mu16[gr] = mean;
            rs16[gr] = rsqrtf(var + 1e-5f);
        }
    }
    __syncthreads();
    {
        float gj = g_t[j], bb = bln_t[j];
#pragma unroll
        for (int r = 0; r < 8; r++) {
            int rr = half * 8 + r;
            float v = fmaxf((T2[rr][j] - mu16[rr]) * rs16[rr] * gj + bb, 0.0f);
            emb[(row0 + rr) * 128 + j] = v;
            T2[rr][j] = v;
        }
    }
    __syncthreads();
    {
        bf16x8 ah[4];
#pragma unroll
        for (int k = 0; k < 4; k++) ah[k] = mk_hi(&T2[lr][k * 32 + lg * 8]);
        const unsigned short* wh0 = Shi + (size_t)col0 * 128 + lg * 8;
        const unsigned short* wh1 = Shi + (size_t)col1 * 128 + lg * 8;
        f32x4 a0 = {0.f, 0.f, 0.f, 0.f}, a1 = {0.f, 0.f, 0.f, 0.f};
#pragma unroll
        for (int k = 0; k < 4; k++) {
            a0 = MFMA(ah[k], *(const bf16x8*)(wh0 + k * 32), a0, 0, 0, 0);
            a1 = MFMA(ah[k], *(const bf16x8*)(wh1 + k * 32), a1, 0, 0, 0);
        }
        float b0 = sb1[col0], b1v = sb1[col1], w20 = sW2[col0], w21 = sW2[col1];
#pragma unroll
        for (int i = 0; i < 4; i++) {
            int r = lg * 4 + i;
            float v = tanhf_fast(a0[i] + b0) * w20 + tanhf_fast(a1[i] + b1v) * w21;
            v += __shfl_xor(v, 1);
            v += __shfl_xor(v, 2);
            v += __shfl_xor(v, 4);
            v += __shfl_xor(v, 8);
            if (lr == 0) part[w][r] = v;
        }
    }
    __syncthreads();
    if (tid < 16)
        scores[(row0 + tid) * 2 + t] = part[0][tid] + part[1][tid] + part[2][tid] + part[3][tid] + eb2[t];
}

// ---------------- TAIL-B1 ----------------
__global__ __launch_bounds__(256) void k_tailB1(const float* __restrict__ emb0,
                                                const float* __restrict__ emb1,
                                                const float* __restrict__ scores,
                                                const unsigned short* __restrict__ Fhi,
                                                const unsigned short* __restrict__ Flo,
                                                const float* __restrict__ eob,
                                                const float* __restrict__ elg,
                                                const float* __restrict__ elb,
                                                float* __restrict__ fused2) {
    __shared__ __align__(16) float T[16][132];
    __shared__ __align__(16) float T2[16][132];
    __shared__ float mu16[16], rs16[16], w0s[16], w1s[16];
    int tid = threadIdx.x;
    long row0 = (long)blockIdx.x * 16;
    if (tid < 16) {
        long r = row0 + tid;
        float s0 = scores[r * 2], s1 = scores[r * 2 + 1];
        float mx = fmaxf(s0, s1);
        float e0 = __expf(s0 - mx), e1 = __expf(s1 - mx);
        float inv = 1.0f / (e0 + e1);
        w0s[tid] = e0 * inv;
        w1s[tid] = e1 * inv;
    }
    __syncthreads();
#pragma unroll
    for (int i = 0; i < 8; i++) {
        int idx = tid + i * 256;
        int r = idx >> 7, c = idx & 127;
        T[r][c] = w0s[r] * emb0[(row0 + r) * 128 + c] + w1s[r] * emb1[(row0 + r) * 128 + c];
    }
    __syncthreads();
    int w = tid >> 6, lane = tid & 63, lr = lane & 15, lg = lane >> 4;
    int col0 = w * 32 + lr, col1 = col0 + 16;
    int j = tid & 127, half = tid >> 7;
    {
        bf16x8 ahi[4], alo[4];
#pragma unroll
        for (int k = 0; k < 4; k++) mk_split(&T[lr][k * 32 + lg * 8], ahi[k], alo[k]);
        const unsigned short* wh0 = Fhi + (size_t)col0 * 128 + lg * 8;
        const unsigned short* wl0 = Flo + (size_t)col0 * 128 + lg * 8;
        const unsigned short* wh1 = Fhi + (size_t)col1 * 128 + lg * 8;
        const unsigned short* wl1 = Flo + (size_t)col1 * 128 + lg * 8;
        f32x4 a0 = {0.f, 0.f, 0.f, 0.f}, a1 = {0.f, 0.f, 0.f, 0.f};
#pragma unroll
        for (int k = 0; k < 4; k++) {
            bf16x8 bh = *(const bf16x8*)(wh0 + k * 32), bl = *(const bf16x8*)(wl0 + k * 32);
            a0 = MFMA(ahi[k], bh, a0, 0, 0, 0);
            a0 = MFMA(alo[k], bh, a0, 0, 0, 0);
            a0 = MFMA(ahi[k], bl, a0, 0, 0, 0);
            bh = *(const bf16x8*)(wh1 + k * 32); bl = *(const bf16x8*)(wl1 + k * 32);
            a1 = MFMA(ahi[k], bh, a1, 0, 0, 0);
            a1 = MFMA(alo[k], bh, a1, 0, 0, 0);
            a1 = MFMA(ahi[k], bl, a1, 0, 0, 0);
        }
#pragma unroll
        for (int i = 0; i < 4; i++) {
            int r = lg * 4 + i;
            T2[r][col0] = a0[i] + eob[col0];
            T2[r][col1] = a1[i] + eob[col1];
        }
    }
    __syncthreads();
    {
        int gr = tid >> 4, l16 = tid & 15;
        float sm = 0.0f, sq = 0.0f;
#pragma unroll
        for (int i = 0; i < 8; i++) {
            float v = T2[gr][l16 + 16 * i];
            sm += v; sq += v * v;
        }
#pragma unroll
        for (int m = 1; m < 16; m <<= 1) { sm += __shfl_xor(sm, m); sq += __shfl_xor(sq, m); }
        if (l16 == 0) {
            float mean = sm * (1.0f / 128.0f);
            float var = sq * (1.0f / 128.0f) - mean * mean;
            mu16[gr] = mean;
            rs16[gr] = rsqrtf(var + 1e-5f);
        }
    }
    __syncthreads();
    {
        float gj = elg[j], bb = elb[j];
#pragma unroll
        for (int r = 0; r < 8; r++) {
            int rr = half * 8 + r;
            float v = fmaxf((T2[rr][j] - mu16[rr]) * rs16[rr] * gj + bb, 0.0f);
            fused2[(row0 + rr) * 128 + j] = v;
        }
    }
}

// ---------------- FSUM ----------------
__global__ __launch_bounds__(256) void k_fsum(const float* __restrict__ fused2,
                                              const int* __restrict__ lev,
                                              float* __restrict__ fsumg) {
    __shared__ float ls[2][4][128];
    int tid = threadIdx.x, half = tid >> 7, j = tid & 127;
#pragma unroll
    for (int l = 0; l < 4; l++) ls[half][l][j] = 0.0f;
    __syncthreads();
    for (long row = (long)blockIdx.x * 2 + half; row < NN; row += (long)gridDim.x * 2) {
        int l = lev[row];
        ls[half][l][j] += fused2[row * 128 + j];
    }
    __syncthreads();
    if (half == 0) {
#pragma unroll
        for (int l = 0; l < 4; l++) atomicAdd(&fsumg[l * 128 + j], ls[0][l][j] + ls[1][l][j]);
    }
}

// ---------------- FIN2 ----------------
__global__ void k_fin2(const float* __restrict__ fsum, const int* __restrict__ cnt4,
                       const float* __restrict__ hpW, const float* __restrict__ hpb,
                       const float* __restrict__ W1b, const float* __restrict__ b1,
                       float* __restrict__ lmean, float* __restrict__ lmw) {
    __shared__ float fs[128];
    __shared__ float lml[128];
    int l = blockIdx.x, j = threadIdx.x;
    fs[j] = fsum[l * 128 + j];
    __syncthreads();
    float c = (float)cnt4[l];
    float a = c * hpb[l * 128 + j];
    const float* wp = hpW + (size_t)l * 16384;
    for (int k = 0; k < 128; k++) a = fmaf(fs[k], wp[k * 128 + j], a);
    float cm = c < 1.0f ? 1.0f : c;
    float v = a / cm;
    lmean[l * 128 + j] = v;
    lml[j] = v;
    __syncthreads();
    float b = b1[j];
    for (int k = 0; k < 128; k++) b = fmaf(lml[k], W1b[k * 128 + j], b);
    lmw[l * 128 + j] = b;
}

// ---------------- TAIL-CD2 (level-bucketed) ----------------
__global__ __launch_bounds__(256) void k_tailCD2(const float* __restrict__ fused2,
                                                 const int* __restrict__ perm,
                                                 const int* __restrict__ cnt4,
                                                 const int* __restrict__ off4,
                                                 const int* __restrict__ boff5,
                                                 const unsigned short* __restrict__ QWhi,
                                                 const unsigned short* __restrict__ QWlo,
                                                 const float* __restrict__ qb,
                                                 const float* __restrict__ lmw,
                                                 const float* __restrict__ lmean,
                                                 const float* __restrict__ hW2,
                                                 const unsigned short* __restrict__ Ohi,
                                                 const unsigned short* __restrict__ Olo,
                                                 const float* __restrict__ hob,
                                                 const float* __restrict__ hlg,
                                                 const float* __restrict__ hlb,
                                                 float* __restrict__ out) {
    __shared__ __align__(16) float T[16][132];
    __shared__ __align__(16) float T2[16][132];
    __shared__ float lm[4][128];
    __shared__ float lmwS[4][128];
    __shared__ float w2S[128];
    __shared__ float scS[16][4];
    __shared__ float aw[16][4];
    __shared__ float mu16[16], rs16[16];
    __shared__ int idx16[16];
    int tid = threadIdx.x;
    int b = blockIdx.x;
    if (b >= boff5[4]) return;
    int l = (b >= boff5[3]) ? 3 : (b >= boff5[2]) ? 2 : (b >= boff5[1]) ? 1 : 0;
    int bi = b - boff5[l];
    int base = off4[l] + bi * 16;
    int last = off4[l] + cnt4[l] - 1;
    if (tid < 16) {
        int gp = base + tid;
        if (gp > last) gp = last;
        idx16[tid] = perm[gp];
    }
    for (int idx = tid; idx < 512; idx += 256) {
        lm[idx >> 7][idx & 127] = lmean[idx];
        lmwS[idx >> 7][idx & 127] = lmw[idx];
    }
    if (tid < 128) w2S[tid] = hW2[tid];
    __syncthreads();
#pragma unroll
    for (int i = 0; i < 8; i++) {
        int idx = tid + i * 256;
        int r = idx >> 7, c = idx & 127;
        T[r][c] = fused2[(size_t)idx16[r] * 128 + c];
    }
    __syncthreads();
    int w = tid >> 6, lane = tid & 63, lr = lane & 15, lg = lane >> 4;
    int col0 = w * 32 + lr, col1 = col0 + 16;
    int j = tid & 127, half = tid >> 7;
    {
        bf16x8 ahi[4], alo[4];
#pragma unroll
        for (int k = 0; k < 4; k++) mk_split(&T[lr][k * 32 + lg * 8], ahi[k], alo[k]);
        const unsigned short* wh0 = QWhi + (size_t)l * 16384 + (size_t)col0 * 128 + lg * 8;
        const unsigned short* wl0 = QWlo + (size_t)l * 16384 + (size_t)col0 * 128 + lg * 8;
        const unsigned short* wh1 = QWhi + (size_t)l * 16384 + (size_t)col1 * 128 + lg * 8;
        const unsigned short* wl1 = QWlo + (size_t)l * 16384 + (size_t)col1 * 128 + lg * 8;
        f32x4 a0 = {0.f, 0.f, 0.f, 0.f}, a1 = {0.f, 0.f, 0.f, 0.f};
#pragma unroll
        for (int k = 0; k < 4; k++) {
            bf16x8 bh = *(const bf16x8*)(wh0 + k * 32), bl = *(const bf16x8*)(wl0 + k * 32);
            a0 = MFMA(ahi[k], bh, a0, 0, 0, 0);
            a0 = MFMA(alo[k], bh, a0, 0, 0, 0);
            a0 = MFMA(ahi[k], bl, a0, 0, 0, 0);
            bh = *(const bf16x8*)(wh1 + k * 32); bl = *(const bf16x8*)(wl1 + k * 32);
            a1 = MFMA(ahi[k], bh, a1, 0, 0, 0);
            a1 = MFMA(alo[k], bh, a1, 0, 0, 0);
            a1 = MFMA(ahi[k], bl, a1, 0, 0, 0);
        }
#pragma unroll
        for (int i = 0; i < 4; i++) {
            int r = lg * 4 + i;
            T2[r][col0] = a0[i] + qb[l * 128 + col0];
            T2[r][col1] = a1[i] + qb[l * 128 + col1];
        }
    }
    __syncthreads();
    {
        int p = tid >> 2, sub = tid & 3;
        int pr = p & 15, pl = p >> 4;
        float s = 0.0f;
#pragma unroll
        for (int jj = 0; jj < 32; jj++) {
            int j2 = sub + 4 * jj;
            s += tanhf_fast(T2[pr][j2] + lmwS[pl][j2]) * w2S[j2];
        }
        s += __shfl_xor(s, 1);
        s += __shfl_xor(s, 2);
        if (sub == 0) scS[pr][pl] = s;
    }
    __syncthreads();
    if (tid < 16) {
        float sc[4];
        float mx = -1e30f;
#pragma unroll
        for (int ll = 0; ll < 4; ll++) {
            sc[ll] = scS[tid][ll];
            mx = fmaxf(mx, sc[ll]);
        }
        float s = 0.0f;
#pragma unroll
        for (int ll = 0; ll < 4; ll++) { sc[ll] = __expf(sc[ll] - mx); s += sc[ll]; }
        float inv = 1.0f / s;
#pragma unroll
        for (int ll = 0; ll < 4; ll++) aw[tid][ll] = sc[ll] * inv;
    }
    __syncthreads();
#pragma unroll
    for (int r = 0; r < 8; r++) {
        int rr = half * 8 + r;
        float e = 0.0f;
#pragma unroll
        for (int ll = 0; ll < 4; ll++) e = fmaf(aw[rr][ll], lm[ll][j], e);
        T[rr][j] = e;
    }
    __syncthreads();
    {
        bf16x8 ahi[4], alo[4];
#pragma unroll
        for (int k = 0; k < 4; k++) mk_split(&T[lr][k * 32 + lg * 8], ahi[k], alo[k]);
        const unsigned short* wh0 = Ohi + (size_t)col0 * 128 + lg * 8;
        const unsigned short* wl0 = Olo + (size_t)col0 * 128 + lg * 8;
        const unsigned short* wh1 = Ohi + (size_t)col1 * 128 + lg * 8;
        const unsigned short* wl1 = Olo + (size_t)col1 * 128 + lg * 8;
        f32x4 a0 = {0.f, 0.f, 0.f, 0.f}, a1 = {0.f, 0.f, 0.f, 0.f};
#pragma unroll
        for (int k = 0; k < 4; k++) {
            bf16x8 bh = *(const bf16x8*)(wh0 + k * 32), bl = *(const bf16x8*)(wl0 + k * 32);
            a0 = MFMA(ahi[k], bh, a0, 0, 0, 0);
            a0 = MFMA(alo[k], bh, a0, 0, 0, 0);
            a0 = MFMA(ahi[k], bl, a0, 0, 0, 0);
            bh = *(const bf16x8*)(wh1 + k * 32); bl = *(const bf16x8*)(wl1 + k * 32);
            a1 = MFMA(ahi[k], bh, a1, 0, 0, 0);
            a1 = MFMA(alo[k], bh, a1, 0, 0, 0);
            a1 = MFMA(ahi[k], bl, a1, 0, 0, 0);
        }
#pragma unroll
        for (int i = 0; i < 4; i++) {
            int r = lg * 4 + i;
            T2[r][col0] = a0[i] + hob[col0];
            T2[r][col1] = a1[i] + hob[col1];
        }
    }
    __syncthreads();
    {
        int gr = tid >> 4, l16 = tid & 15;
        float sm = 0.0f, sq = 0.0f;
#pragma unroll
        for (int i = 0; i < 8; i++) {
            float v = T2[gr][l16 + 16 * i];
            sm += v; sq += v * v;
        }
#pragma unroll
        for (int m = 1; m < 16; m <<= 1) { sm += __shfl_xor(sm, m); sq += __shfl_xor(sq, m); }
        if (l16 == 0) {
            float mean = sm * (1.0f / 128.0f);
            float var = sq * (1.0f / 128.0f) - mean * mean;
            mu16[gr] = mean;
            rs16[gr] = rsqrtf(var + 1e-5f);
        }
    }
    __syncthreads();
    {
        float gj = hlg[j], bb = hlb[j];
#pragma unroll
        for (int r = 0; r < 8; r++) {
            int rr = half * 8 + r;
            float v = (T2[rr][j] - mu16[rr]) * rs16[rr] * gj + bb;
            out[(size_t)idx16[rr] * 128 + j] = fmaxf(v, 0.0f);
        }
    }
}

extern "C" void kernel_launch(void* const* d_in, const int* in_sizes, int n_in,
                              void* d_out, int out_size, void* d_ws, size_t ws_size,
                              hipStream_t stream) {
    const float* nf  = (const float*)d_in[0];
    const float* ef  = (const float*)d_in[1];
    const int*   lev = (const int*)d_in[2];
    const int*   ei  = (const int*)d_in[3];
    const float* nlW = (const float*)d_in[4];
    const float* nlb = (const float*)d_in[5];
    const float* neW = (const float*)d_in[6];
    const float* neb = (const float*)d_in[7];
    const float* aW1 = (const float*)d_in[8];
    const float* ab1 = (const float*)d_in[9];
    const float* aW2 = (const float*)d_in[10];
    const float* ab2 = (const float*)d_in[11];
    const float* oW  = (const float*)d_in[12];
    const float* ob  = (const float*)d_in[13];
    const float* lng = (const float*)d_in[14];
    const float* lnb = (const float*)d_in[15];
    const float* eW1 = (const float*)d_in[16];
    const float* eb1 = (const float*)d_in[17];
    const float* eW2 = (const float*)d_in[18];
    const float* eb2 = (const float*)d_in[19];
    const float* eoW = (const float*)d_in[20];
    const float* eob = (const float*)d_in[21];
    const float* elg = (const float*)d_in[22];
    const float* elb = (const float*)d_in[23];
    const float* hpW = (const float*)d_in[24];
    const float* hpb = (const float*)d_in[25];
    const float* hW1 = (const float*)d_in[26];
    const float* hb1 = (const float*)d_in[27];
    const float* hW2 = (const float*)d_in[28];
    const float* hb2 = (const float*)d_in[29];
    const float* hoW = (const float*)d_in[30];
    const float* hob = (const float*)d_in[31];
    const float* hlg = (const float*)d_in[32];
    const float* hlb = (const float*)d_in[33];

    float* ws = (float*)d_ws;
    size_t NH = (size_t)NN * 128;
    float* fused2 = ws;                       // NH
    float* emb0   = fused2 + NH;              // NH
    float* emb1   = emb0 + NH;                // NH
    float* ebuf2  = emb1 + NH;                // 2*EE (CSR order)
    float* scores = ebuf2 + 2 * (size_t)EE;   // 2*NN
    float* beff2  = scores + (size_t)2 * NN;  // 256
    float* fsum   = beff2 + 256;              // 512
    float* lmean  = fsum + 512;               // 512
    float* lmw    = lmean + 512;              // 512
    float* qb     = lmw + 512;                // 512
    float* obf    = qb + 512;                 // 256
    unsigned short* U2    = (unsigned short*)(obf + 256); // 2*NH
    unsigned short* V2    = U2 + 2 * NH;                  // 2*NH
    unsigned short* nfbf  = V2 + 2 * NH;                  // NH
    unsigned short* WUT2  = nfbf + NH;                    // 2*16384
    unsigned short* WVT2  = WUT2 + 2 * 16384;
    unsigned short* WET2  = WVT2 + 2 * 16384;             // 2*8192
    unsigned short* twhi  = WET2 + 2 * 8192;              // 4*16384
    unsigned short* twlo  = twhi + 4 * 16384;             // 4*16384
    unsigned short* foldhi = twlo + 4 * 16384;            // 2*16384
    unsigned short* foldlo = foldhi + 2 * 16384;          // 2*16384
    unsigned short* QWhi  = foldlo + 2 * 16384;           // 4*16384
    unsigned short* QWlo  = QWhi + 4 * 16384;             // 4*16384
    int* perm    = (int*)(QWlo + 4 * 16384);              // NN
    int* cnt4    = perm + NN;
    int* off4    = cnt4 + 4;
    int* boff5   = off4 + 4;
    int* cursorL = boff5 + 5;
    int* deg2    = cursorL + 4;          // 2*NN
    int* rowptr2 = deg2 + 2 * NN;        // 2*NN+1
    int* cursor2 = rowptr2 + 2 * NN + 1; // 2*NN
    int* stmp    = cursor2 + 2 * NN;     // 2*NN
    int* sbsum   = stmp + 2 * NN;        // 512
    int* sboff   = sbsum + 512;          // 512
    int* ceid2   = sboff + 512;          // 2*EE
    int* cs2     = ceid2 + 2 * EE;       // 2*EE
    int* cdst2   = cs2 + 2 * EE;         // 2*EE
    float* out = (float*)d_out;

    WSrc ps;
    ps.s[0] = eW1;              // score W1 t0
    ps.s[1] = eW1 + 16384;      // score W1 t1
    ps.s[2] = eoW;
    ps.s[3] = hoW;

    const int NB_N = NN / 16;             // 6250
    const int SCB = (2 * NN + 511) / 512; // 391

    // level bucketing
    k_zeroi<<<1, 4, 0, stream>>>(cnt4, 4);
    k_count<<<128, 256, 0, stream>>>(lev, cnt4);
    k_scan<<<1, 1, 0, stream>>>(cnt4, off4, boff5, cursorL);
    k_scatter<<<125, 256, 0, stream>>>(lev, cursorL, perm);

    // weight prep
    k_prep_tail<<<4 * 64, 256, 0, stream>>>(ps, twhi, twlo);
    k_prep_fold<<<129, 256, 0, stream>>>(nlW, nlb, oW, ob, foldhi, foldlo, obf);
    k_prep_q<<<258, 256, 0, stream>>>(hpW, hpb, hW1, QWhi, QWlo, qb);
    k_zero<<<1, 512, 0, stream>>>(fsum, (size_t)512);

    // nf -> bf16 (shared gather source)
    k_nfcvt<<<NH_C / 8 / 256, 256, 0, stream>>>(nf, nfbf);

    // CSR build (both relations at once)
    k_zeroi<<<(2 * NN + 255) / 256, 256, 0, stream>>>(deg2, 2 * NN);
    k_hist2<<<(2 * EE + 255) / 256, 256, 0, stream>>>(ei, deg2);
    k_scan1<<<SCB, 512, 0, stream>>>(deg2, stmp, sbsum);
    k_scan2<<<1, 512, 0, stream>>>(sbsum, sboff, SCB);
    k_scan3<<<SCB, 512, 0, stream>>>(deg2, stmp, sboff, rowptr2, cursor2);
    k_csr_scatter3<<<(2 * EE + 255) / 256, 256, 0, stream>>>(ei, cursor2, ceid2, cs2, cdst2);

    // head (both t, one nf pass): U,V only
    k_prep_head2<<<256, 128, 0, stream>>>(nlW, nlb, aW1, ab1, neW, neb,
                                          WUT2, WVT2, WET2, beff2);
    k_head2b<<<NB_N, 256, 0, stream>>>(nf, WUT2, WVT2, U2, V2);

    // edge scores (CSR order, both t)
    k_edge5<<<2 * EE / EBLK, 256, 0, stream>>>(ef, ceid2, cs2, cdst2, WET2, U2, V2,
                                               beff2, aW2, ab2, ebuf2);
    // aggregation (nfbf gather) + folded GEMM + relation tail (both t)
    k_tailA2c<<<2 * NB_N, 256, 0, stream>>>(rowptr2, cdst2, ebuf2, nfbf,
                                            foldhi, foldlo, twhi, obf,
                                            lng, lnb, eb1, eW2, eb2,
                                            emb0, emb1, scores, NB_N);

    k_tailB1<<<NB_N, 256, 0, stream>>>(emb0, emb1, scores,
                                       twhi + (size_t)2 * 16384, twlo + (size_t)2 * 16384,
                                       eob, elg, elb, fused2);
    k_fsum<<<256, 256, 0, stream>>>(fused2, lev, fsum);
    k_fin2<<<4, 128, 0, stream>>>(fsum, cnt4, hpW, hpb, hW1 + 16384, hb1, lmean, lmw);
    k_tailCD2<<<NB_N + 4, 256, 0, stream>>>(fused2, perm, cnt4, off4, boff5,
                                            QWhi, QWlo, qb, lmw, lmean, hW2,
                                            twhi + (size_t)3 * 16384, twlo + (size_t)3 * 16384,
                                            hob, hlg, hlb, out);
}